// Round 2
// baseline (8041.663 us; speedup 1.0000x reference)
//
#include <hip/hip_runtime.h>
#include <hip/hip_bf16.h>
#include <stdint.h>

// Bidirectional 2-layer LSTM, B=32, T=2048, F=H=128, gates G=4H=512.
// Phases: prep (swizzle Wx->bf16 frags) -> input_proj L0 -> scan L0 (fwd+bwd,
// 2 persistent workgroups) -> input_proj L1 -> scan L1 (writes d_out).

#define DEVINL __device__ __forceinline__

typedef __attribute__((ext_vector_type(8))) short short8;
typedef __attribute__((ext_vector_type(4))) float f32x4;

static constexpr int B = 32, T = 2048, F = 128, H = 128, G = 512;
static constexpr size_t XOUT = (size_t)B * T * 256;  // 16,777,216 elements

DEVINL unsigned short f2bf(float f) {
  unsigned int u = __float_as_uint(f);
  u += 0x7FFFu + ((u >> 16) & 1u);           // RNE
  return (unsigned short)(u >> 16);
}
DEVINL float fsig(float x) {                  // 1/(1+e^-x)
  float e = __builtin_amdgcn_exp2f(-1.4426950408889634f * x);
  return __builtin_amdgcn_rcpf(1.0f + e);
}
DEVINL float ftanh(float x) {                 // 2*sig(2x)-1
  float e = __builtin_amdgcn_exp2f(-2.8853900817779268f * x);
  return 2.0f * __builtin_amdgcn_rcpf(1.0f + e) - 1.0f;
}
DEVINL void g2l16(const void* g, void* l) {
  __builtin_amdgcn_global_load_lds((const __attribute__((address_space(1))) unsigned int*)g,
                                   (__attribute__((address_space(3))) unsigned int*)l,
                                   16, 0, 0);
}

// ---------------------------------------------------------------------------
// Prep: Wx (f32, [K][512]) -> bf16 B-fragment order [dir][ng(32)][ks][lane(64)][e(8)]
//   col = ng*16 + (lane&15); k = ks*32 + (lane>>4)*8 + e
// ---------------------------------------------------------------------------
__global__ __launch_bounds__(256) void prep_wx(const float* wxf0, const float* wxb0,
                                               const float* wxf1, const float* wxb1,
                                               unsigned short* sw0, unsigned short* sw1) {
  int idx = blockIdx.x * 256 + threadIdx.x;
  if (idx < 2 * 65536) {                       // layer 0, KS=4
    int d = idx >> 16;
    int local = idx & 65535;
    const float* w = d ? wxb0 : wxf0;
    int e = local & 7, lane = (local >> 3) & 63, ks = (local >> 9) & 3, ng = local >> 11;
    int col = ng * 16 + (lane & 15);
    int k = ks * 32 + ((lane >> 4) << 3) + e;
    sw0[idx] = f2bf(w[k * 512 + col]);
  } else {                                     // layer 1, KS=8
    int j = idx - 2 * 65536;
    if (j < 2 * 131072) {
      int d = j >> 17;
      int local = j & 131071;
      const float* w = d ? wxb1 : wxf1;
      int e = local & 7, lane = (local >> 3) & 63, ks = (local >> 9) & 7, ng = local >> 12;
      int col = ng * 16 + (lane & 15);
      int k = ks * 32 + ((lane >> 4) << 3) + e;
      sw1[j] = f2bf(w[k * 512 + col]);
    }
  }
}

// ---------------------------------------------------------------------------
// Input projection: xp[dir][t][32x512] = A(t) @ Wx + b, stored in D-fragment
// order: f32x4 index = t*4096 + (ng*2+mt)*64 + lane   (per dir)
// LAYER 0: A = x (f32, [b][t][128]);  LAYER 1: A = out0 (bf16, [t*32+b][256])
// ---------------------------------------------------------------------------
template <int LAYER, bool XPF32>
__global__ __launch_bounds__(256) void input_proj(const float* x, const unsigned short* a_bf,
                                                  const unsigned short* wsw,
                                                  const float* bias_f, const float* bias_b,
                                                  void* xp_out) {
  constexpr int KS = (LAYER == 0) ? 4 : 8;
  int t = blockIdx.x, dir = blockIdx.y;
  int wid = threadIdx.x >> 6, lane = threadIdx.x & 63;
  const unsigned short* wbase = wsw + (size_t)dir * (32 * KS * 64 * 8);
  const float* bias = dir ? bias_b : bias_f;

  short8 afrag[2][KS];
#pragma unroll
  for (int mt = 0; mt < 2; ++mt) {
#pragma unroll
    for (int ks = 0; ks < KS; ++ks) {
      int m = (lane & 15) + mt * 16;
      int kk = ks * 32 + ((lane >> 4) << 3);
      if constexpr (LAYER == 0) {
        const float* ap = x + (size_t)m * (T * F) + (size_t)t * F + kk;
        float4 lo = *(const float4*)ap;
        float4 hi = *(const float4*)(ap + 4);
        short8 s;
        s[0] = (short)f2bf(lo.x); s[1] = (short)f2bf(lo.y);
        s[2] = (short)f2bf(lo.z); s[3] = (short)f2bf(lo.w);
        s[4] = (short)f2bf(hi.x); s[5] = (short)f2bf(hi.y);
        s[6] = (short)f2bf(hi.z); s[7] = (short)f2bf(hi.w);
        afrag[mt][ks] = s;
      } else {
        afrag[mt][ks] = *(const short8*)(a_bf + ((size_t)t * 32 + m) * 256 + kk);
      }
    }
  }

#pragma unroll
  for (int ngi = 0; ngi < 8; ++ngi) {
    int ng = wid * 8 + ngi;
    f32x4 acc0 = {0.f, 0.f, 0.f, 0.f};
    f32x4 acc1 = {0.f, 0.f, 0.f, 0.f};
#pragma unroll
    for (int ks = 0; ks < KS; ++ks) {
      short8 b = *(const short8*)(wbase + ((size_t)(ng * KS + ks) * 64 + lane) * 8);
      acc0 = __builtin_amdgcn_mfma_f32_16x16x32_bf16(afrag[0][ks], b, acc0, 0, 0, 0);
      acc1 = __builtin_amdgcn_mfma_f32_16x16x32_bf16(afrag[1][ks], b, acc1, 0, 0, 0);
    }
    float bs = bias[ng * 16 + (lane & 15)];
#pragma unroll
    for (int mt = 0; mt < 2; ++mt) {
      f32x4 v = (mt == 0) ? acc0 : acc1;
      v[0] += bs; v[1] += bs; v[2] += bs; v[3] += bs;
      size_t idx4 = (size_t)t * 4096 + ((size_t)ng * 2 + mt) * 64 + lane;
      if constexpr (XPF32) {
        ((f32x4*)xp_out)[(size_t)dir * 8388608 + idx4] = v;
      } else {
        unsigned int lo = (unsigned)f2bf(v[0]) | ((unsigned)f2bf(v[1]) << 16);
        unsigned int hi = (unsigned)f2bf(v[2]) | ((unsigned)f2bf(v[3]) << 16);
        uint2 u; u.x = lo; u.y = hi;
        *(uint2*)((unsigned short*)xp_out + (size_t)dir * 33554432 + idx4 * 4) = u;
      }
    }
  }
}

// ---------------------------------------------------------------------------
// Persistent LSTM scan: 1 workgroup (8 waves) per direction (blockIdx.x=dir).
// Wave w owns hidden cols [w*16, w*16+16) for all 4 gates. Wh lives in
// registers as bf16 B-frags; h in LDS (bf16, XOR-swizzled); c in fp32 regs.
// gx is double-buffered in LDS via global_load_lds, prefetched 1 step ahead.
// ---------------------------------------------------------------------------
template <bool XPF32>
DEVINL void prefetch_step(const unsigned char* xp_dir, int t, unsigned char* dst,
                          int wid, int lane) {
  constexpr int NL = XPF32 ? 8 : 4;
  constexpr int STEPB = XPF32 ? 65536 : 32768;
  const unsigned char* src = xp_dir + (size_t)t * STEPB;
#pragma unroll
  for (int j = 0; j < NL; ++j) {
    int off = (wid * NL + j) * 1024;
    g2l16(src + off + lane * 16, dst + off);
  }
}

template <int LAYER, bool XPF32>
__global__ __launch_bounds__(512, 2) void lstm_scan(const void* xp,
                                                    const float* wh_f, const float* wh_b,
                                                    unsigned short* out0, float* dout) {
  constexpr int GXB = XPF32 ? 65536 : 32768;
  int dir = blockIdx.x;
  int wid = threadIdx.x >> 6, lane = threadIdx.x & 63;

  __shared__ __align__(16) unsigned char gxbuf[2][GXB];
  __shared__ __align__(16) unsigned char hbuf[8192];  // [b=32][j=128] bf16, swizzled

  const float* wh = dir ? wh_b : wh_f;

  // Wh -> register B-fragments: whf[gate][ks], col = g*128 + wid*16 + (lane&15)
  short8 whf[4][4];
#pragma unroll
  for (int g = 0; g < 4; ++g) {
#pragma unroll
    for (int ks = 0; ks < 4; ++ks) {
      short8 s;
#pragma unroll
      for (int e = 0; e < 8; ++e) {
        int k = ks * 32 + ((lane >> 4) << 3) + e;
        int col = g * 128 + wid * 16 + (lane & 15);
        s[e] = (short)f2bf(wh[k * 512 + col]);
      }
      whf[g][ks] = s;
    }
  }

  for (int i = threadIdx.x; i < 2048; i += 512) ((unsigned int*)hbuf)[i] = 0u;

  f32x4 c0 = {0.f, 0.f, 0.f, 0.f};
  f32x4 c1 = {0.f, 0.f, 0.f, 0.f};

  const unsigned char* xpd =
      (const unsigned char*)xp + (size_t)dir * (XPF32 ? 134217728u : 67108864u);

  prefetch_step<XPF32>(xpd, dir ? (T - 1) : 0, gxbuf[0], wid, lane);
  __syncthreads();

  for (int s = 0; s < T; ++s) {
    int t = dir ? (T - 1 - s) : s;
    int cur = s & 1;

    // h_{t-1} A-fragments from LDS (swizzled)
    short8 af[2][4];
#pragma unroll
    for (int mt = 0; mt < 2; ++mt) {
#pragma unroll
      for (int ks = 0; ks < 4; ++ks) {
        int m = (lane & 15) + mt * 16;
        int kb = (ks * 32 + ((lane >> 4) << 3)) * 2;
        af[mt][ks] = *(const short8*)(hbuf + m * 256 + (kb ^ ((m & 7) << 4)));
      }
    }

    // acc init = gx (D-fragment layout)
    f32x4 acc[4][2];
#pragma unroll
    for (int g = 0; g < 4; ++g) {
#pragma unroll
      for (int mt = 0; mt < 2; ++mt) {
        int fi = ((g * 8 + wid) * 2 + mt) * 64 + lane;
        if constexpr (XPF32) {
          acc[g][mt] = ((const f32x4*)gxbuf[cur])[fi];
        } else {
          uint2 u = *(const uint2*)((const unsigned short*)gxbuf[cur] + (size_t)fi * 4);
          f32x4 v;
          v[0] = __uint_as_float(u.x << 16);
          v[1] = __uint_as_float(u.x & 0xFFFF0000u);
          v[2] = __uint_as_float(u.y << 16);
          v[3] = __uint_as_float(u.y & 0xFFFF0000u);
          acc[g][mt] = v;
        }
      }
    }

    // g += h @ Wh
#pragma unroll
    for (int g = 0; g < 4; ++g)
#pragma unroll
      for (int mt = 0; mt < 2; ++mt)
#pragma unroll
        for (int ks = 0; ks < 4; ++ks)
          acc[g][mt] = __builtin_amdgcn_mfma_f32_16x16x32_bf16(af[mt][ks], whf[g][ks],
                                                               acc[g][mt], 0, 0, 0);

    __syncthreads();  // all LDS reads of h_{t-1}/gx done before overwrite

    if (s + 1 < T)
      prefetch_step<XPF32>(xpd, dir ? (T - 2 - s) : (s + 1), gxbuf[cur ^ 1], wid, lane);

    // gates + state update + h writes (lane-local: acc tiles share (b,col))
#pragma unroll
    for (int mt = 0; mt < 2; ++mt) {
#pragma unroll
      for (int r = 0; r < 4; ++r) {
        float pi = acc[0][mt][r], pf = acc[1][mt][r];
        float pg = acc[2][mt][r], po = acc[3][mt][r];
        float ig = fsig(pi), fg = fsig(pf), gg = ftanh(pg), og = fsig(po);
        float cprev = (mt == 0) ? c0[r] : c1[r];
        float cn = fg * cprev + ig * gg;
        if (mt == 0) c0[r] = cn; else c1[r] = cn;
        float h = og * ftanh(cn);
        unsigned short hb = f2bf(h);
        int b = mt * 16 + ((lane >> 4) << 2) + r;
        int col = wid * 16 + (lane & 15);
        int kb = col * 2;
        *(unsigned short*)(hbuf + b * 256 + (kb ^ ((b & 7) << 4))) = hb;
        if constexpr (LAYER == 0) {
          out0[((size_t)t * 32 + b) * 256 + dir * 128 + col] = hb;
        } else {
          dout[((size_t)b * T + t) * 256 + dir * 128 + col] = h;
        }
      }
    }

    __syncthreads();  // h_t visible (and prefetch drained) before next step
  }

  if constexpr (LAYER == 1) {
#pragma unroll
    for (int mt = 0; mt < 2; ++mt) {
#pragma unroll
      for (int r = 0; r < 4; ++r) {
        int b = mt * 16 + ((lane >> 4) << 2) + r;
        int col = wid * 16 + (lane & 15);
        dout[XOUT + (size_t)b * 256 + dir * 128 + col] = (mt == 0) ? c0[r] : c1[r];
      }
    }
  }
}

// ---------------------------------------------------------------------------
extern "C" void kernel_launch(void* const* d_in, const int* in_sizes, int n_in,
                              void* d_out, int out_size, void* d_ws, size_t ws_size,
                              hipStream_t stream) {
  const float* x    = (const float*)d_in[0];
  const float* wxf0 = (const float*)d_in[1];
  const float* whf0 = (const float*)d_in[2];
  const float* wxb0 = (const float*)d_in[3];
  const float* whb0 = (const float*)d_in[4];
  const float* wxf1 = (const float*)d_in[5];
  const float* whf1 = (const float*)d_in[6];
  const float* wxb1 = (const float*)d_in[7];
  const float* whb1 = (const float*)d_in[8];
  const float* bf0  = (const float*)d_in[9];
  const float* bb0  = (const float*)d_in[10];
  const float* bf1  = (const float*)d_in[11];
  const float* bb1  = (const float*)d_in[12];
  float* dout = (float*)d_out;

  // ws: [xp (2 dirs, reused by layer1)][out0 bf16][sw0][sw1]
  const size_t needF32 = 268435456u + 33554432u + 262144u + 524288u;  // 302,776,320
  bool xpf32 = ws_size >= needF32;
  size_t xpBytes = xpf32 ? 268435456u : 134217728u;
  unsigned char* ws = (unsigned char*)d_ws;
  void* xp = (void*)ws;
  unsigned short* out0 = (unsigned short*)(ws + xpBytes);
  unsigned short* sw0  = (unsigned short*)(ws + xpBytes + 33554432u);
  unsigned short* sw1  = sw0 + 2 * 65536;

  prep_wx<<<1536, 256, 0, stream>>>(wxf0, wxb0, wxf1, wxb1, sw0, sw1);

  if (xpf32) {
    input_proj<0, true><<<dim3(2048, 2), 256, 0, stream>>>(x, nullptr, sw0, bf0, bb0, xp);
    lstm_scan<0, true><<<2, 512, 0, stream>>>(xp, whf0, whb0, out0, nullptr);
    input_proj<1, true><<<dim3(2048, 2), 256, 0, stream>>>(nullptr, out0, sw1, bf1, bb1, xp);
    lstm_scan<1, true><<<2, 512, 0, stream>>>(xp, whf1, whb1, nullptr, dout);
  } else {
    input_proj<0, false><<<dim3(2048, 2), 256, 0, stream>>>(x, nullptr, sw0, bf0, bb0, xp);
    lstm_scan<0, false><<<2, 512, 0, stream>>>(xp, whf0, whb0, out0, nullptr);
    input_proj<1, false><<<dim3(2048, 2), 256, 0, stream>>>(nullptr, out0, sw1, bf1, bb1, xp);
    lstm_scan<1, false><<<2, 512, 0, stream>>>(xp, whf1, whb1, nullptr, dout);
  }
}

// Round 3
// 3401.717 us; speedup vs baseline: 2.3640x; 2.3640x over previous
//
#include <hip/hip_runtime.h>
#include <hip/hip_bf16.h>
#include <stdint.h>

// Bidirectional 2-layer LSTM, B=32, T=2048, F=H=128, G=4H=512.
// prep (Wx,Wh -> scaled bf16 frags) -> proj L0 -> scan L0 (4 WGs: dir x bhalf)
// -> proj L1 -> scan L1. Gate pre-activations are pre-scaled by -log2e
// (i,f,o) / -2log2e (g) so sigmoid = rcp(1+exp2(y)).

#define DEVINL __device__ __forceinline__

typedef __attribute__((ext_vector_type(8))) short short8;
typedef __attribute__((ext_vector_type(4))) float f32x4;

static constexpr int T = 2048;
static constexpr size_t XOUT = (size_t)32 * T * 256;
static constexpr float L2E = 1.4426950408889634f;
static constexpr float M2L2E = -2.8853900817779268f;

DEVINL unsigned short f2bf(float f) {
  unsigned int u = __float_as_uint(f);
  u += 0x7FFFu + ((u >> 16) & 1u);  // RNE
  return (unsigned short)(u >> 16);
}
DEVINL float gate_scale(int g) { return (g == 2) ? M2L2E : -L2E; }

// ---------------------------------------------------------------------------
// prep_wx: Wx (f32 [K][512]) -> scaled bf16 B-frags [dir][ng(32)][ks][lane][e8]
// ---------------------------------------------------------------------------
__global__ __launch_bounds__(256) void prep_wx(const float* wxf0, const float* wxb0,
                                               const float* wxf1, const float* wxb1,
                                               unsigned short* sw0, unsigned short* sw1) {
  int idx = blockIdx.x * 256 + threadIdx.x;
  if (idx < 2 * 65536) {                       // layer 0, KS=4
    int d = idx >> 16;
    int local = idx & 65535;
    const float* w = d ? wxb0 : wxf0;
    int e = local & 7, lane = (local >> 3) & 63, ks = (local >> 9) & 3, ng = local >> 11;
    int col = ng * 16 + (lane & 15);
    int k = ks * 32 + ((lane >> 4) << 3) + e;
    sw0[idx] = f2bf(w[k * 512 + col] * gate_scale(ng >> 3));
  } else {                                     // layer 1, KS=8
    int j = idx - 2 * 65536;
    if (j < 2 * 131072) {
      int d = j >> 17;
      int local = j & 131071;
      const float* w = d ? wxb1 : wxf1;
      int e = local & 7, lane = (local >> 3) & 63, ks = (local >> 9) & 7, ng = local >> 12;
      int col = ng * 16 + (lane & 15);
      int k = ks * 32 + ((lane >> 4) << 3) + e;
      sw1[j] = f2bf(w[k * 512 + col] * gate_scale(ng >> 3));
    }
  }
}

// ---------------------------------------------------------------------------
// prep_wh: Wh (f32 [128][512]) -> scaled bf16 frags, contiguous per (wave):
// idx bits: e(0-2) lane(3-8) wid(9-11) ks(12-13) g(14-15) dir(16) layer(17)
// ---------------------------------------------------------------------------
__global__ __launch_bounds__(256) void prep_wh(const float* whf0, const float* whb0,
                                               const float* whf1, const float* whb1,
                                               unsigned short* swh) {
  int idx = blockIdx.x * 256 + threadIdx.x;
  if (idx >= 262144) return;
  int e = idx & 7, lane = (idx >> 3) & 63, wid = (idx >> 9) & 7;
  int ks = (idx >> 12) & 3, g = (idx >> 14) & 3, dir = (idx >> 16) & 1, layer = (idx >> 17) & 1;
  const float* w = layer ? (dir ? whb1 : whf1) : (dir ? whb0 : whf0);
  int col = g * 128 + wid * 16 + (lane & 15);
  int k = ks * 32 + ((lane >> 4) << 3) + e;
  swh[idx] = f2bf(w[k * 512 + col] * gate_scale(g));
}

// ---------------------------------------------------------------------------
// input_proj: xp[dir][t][32x512] = A(t) @ Wx_scaled + b_scaled, D-frag order:
// f32x4 index = t*4096 + (ng*2+mt)*64 + lane
// ---------------------------------------------------------------------------
template <int LAYER, bool XPF32>
__global__ __launch_bounds__(256) void input_proj(const float* x, const unsigned short* a_bf,
                                                  const unsigned short* wsw,
                                                  const float* bias_f, const float* bias_b,
                                                  void* xp_out) {
  constexpr int KS = (LAYER == 0) ? 4 : 8;
  int t = blockIdx.x, dir = blockIdx.y;
  int wid = threadIdx.x >> 6, lane = threadIdx.x & 63;
  const unsigned short* wbase = wsw + (size_t)dir * (32 * KS * 64 * 8);
  const float* bias = dir ? bias_b : bias_f;

  short8 afrag[2][KS];
#pragma unroll
  for (int mt = 0; mt < 2; ++mt) {
#pragma unroll
    for (int ks = 0; ks < KS; ++ks) {
      int m = (lane & 15) + mt * 16;
      int kk = ks * 32 + ((lane >> 4) << 3);
      if constexpr (LAYER == 0) {
        const float* ap = x + (size_t)m * (T * 128) + (size_t)t * 128 + kk;
        float4 lo = *(const float4*)ap;
        float4 hi = *(const float4*)(ap + 4);
        short8 s;
        s[0] = (short)f2bf(lo.x); s[1] = (short)f2bf(lo.y);
        s[2] = (short)f2bf(lo.z); s[3] = (short)f2bf(lo.w);
        s[4] = (short)f2bf(hi.x); s[5] = (short)f2bf(hi.y);
        s[6] = (short)f2bf(hi.z); s[7] = (short)f2bf(hi.w);
        afrag[mt][ks] = s;
      } else {
        afrag[mt][ks] = *(const short8*)(a_bf + ((size_t)t * 32 + m) * 256 + kk);
      }
    }
  }

#pragma unroll
  for (int ngi = 0; ngi < 8; ++ngi) {
    int ng = wid * 8 + ngi;
    f32x4 acc0 = {0.f, 0.f, 0.f, 0.f};
    f32x4 acc1 = {0.f, 0.f, 0.f, 0.f};
#pragma unroll
    for (int ks = 0; ks < KS; ++ks) {
      short8 b = *(const short8*)(wbase + ((size_t)(ng * KS + ks) * 64 + lane) * 8);
      acc0 = __builtin_amdgcn_mfma_f32_16x16x32_bf16(afrag[0][ks], b, acc0, 0, 0, 0);
      acc1 = __builtin_amdgcn_mfma_f32_16x16x32_bf16(afrag[1][ks], b, acc1, 0, 0, 0);
    }
    float bs = bias[ng * 16 + (lane & 15)] * gate_scale(ng >> 3);
#pragma unroll
    for (int mt = 0; mt < 2; ++mt) {
      f32x4 v = (mt == 0) ? acc0 : acc1;
      v[0] += bs; v[1] += bs; v[2] += bs; v[3] += bs;
      size_t idx4 = (size_t)t * 4096 + ((size_t)ng * 2 + mt) * 64 + lane;
      if constexpr (XPF32) {
        ((f32x4*)xp_out)[(size_t)dir * 8388608 + idx4] = v;
      } else {
        unsigned int lo = (unsigned)f2bf(v[0]) | ((unsigned)f2bf(v[1]) << 16);
        unsigned int hi = (unsigned)f2bf(v[2]) | ((unsigned)f2bf(v[3]) << 16);
        uint2 u; u.x = lo; u.y = hi;
        *(uint2*)((unsigned short*)xp_out + (size_t)dir * 33554432 + idx4 * 4) = u;
      }
    }
  }
}

// ---------------------------------------------------------------------------
// lstm_scan: 4 persistent WGs (blockIdx = dir*2 + batch-half), 8 waves each.
// Wave wid owns 16 hidden cols (all 4 gates). Wh in regs; h double-buffered
// in LDS (XOR-swizzled); gx prefetched into registers; c in regs.
// One lgkm-only barrier per step.
// ---------------------------------------------------------------------------
DEVINL f32x4 gx2f(f32x4 v) { return v; }
DEVINL f32x4 gx2f(uint2 u) {
  f32x4 v;
  v[0] = __uint_as_float(u.x << 16);
  v[1] = __uint_as_float(u.x & 0xFFFF0000u);
  v[2] = __uint_as_float(u.y << 16);
  v[3] = __uint_as_float(u.y & 0xFFFF0000u);
  return v;
}

template <int LAYER, bool XPF32>
__global__ __launch_bounds__(512, 2) void lstm_scan(const void* xp, const unsigned short* swh,
                                                    unsigned short* out0, float* dout) {
  using gxT = typename std::conditional<XPF32, f32x4, uint2>::type;
  int dir = blockIdx.x >> 1;
  int mh = blockIdx.x & 1;
  int wid = threadIdx.x >> 6, lane = threadIdx.x & 63;
  int m = lane & 15;
  int khi = (lane >> 4) << 3;

  __shared__ __align__(16) unsigned short hA[2048];  // 16 rows x 128 cols bf16
  __shared__ __align__(16) unsigned short hB[2048];

  // Wh fragments (pre-scaled, pre-fragged): 16 contiguous b128 loads
  const unsigned short* whbase = swh + (size_t)LAYER * 131072 + (size_t)dir * 65536;
  short8 whf[4][4];
#pragma unroll
  for (int g = 0; g < 4; ++g)
#pragma unroll
    for (int ks = 0; ks < 4; ++ks)
      whf[g][ks] = *(const short8*)(whbase + g * 16384 + ks * 4096 + wid * 512 + lane * 8);

  for (int i = threadIdx.x; i < 1024; i += 512) {
    ((unsigned int*)hA)[i] = 0u;
    ((unsigned int*)hB)[i] = 0u;
  }

  // LDS read offsets (A-frags of h), swizzled
  int aoff[4];
#pragma unroll
  for (int ks = 0; ks < 4; ++ks) {
    int kb = ks * 64 + khi * 2;
    aoff[ks] = m * 256 + (kb ^ ((m & 7) << 4));
  }
  // LDS write offsets for h
  int col = wid * 16 + m;
  int b0r = (lane >> 4) << 2;
  int woff[4];
#pragma unroll
  for (int r = 0; r < 4; ++r) {
    int row = b0r + r;
    woff[r] = row * 256 + ((col * 2) ^ ((row & 7) << 4));
  }

  // gx addressing (xp is in D-frag order)
  const gxT* xpg = (const gxT*)((const unsigned char*)xp +
                                (size_t)dir * (XPF32 ? 134217728u : 67108864u));
  int ob0 = ((0 * 8 + wid) * 2 + mh) * 64 + lane;
  int ob1 = ((1 * 8 + wid) * 2 + mh) * 64 + lane;
  int ob2 = ((2 * 8 + wid) * 2 + mh) * 64 + lane;
  int ob3 = ((3 * 8 + wid) * 2 + mh) * 64 + lane;

  int b0 = mh * 16 + b0r;                       // global batch row base
  size_t obout = (size_t)b0 * 256 + dir * 128 + col;     // layer0 out
  size_t dpb = (size_t)b0 * T * 256 + dir * 128 + col;   // layer1 out

  f32x4 cst = {0.f, 0.f, 0.f, 0.f};

  int t0 = dir ? (T - 1) : 0;
  int ts = dir ? -1 : 1;

  gxT gx0, gx1, gx2, gx3;
  {
    const gxT* x0 = xpg + (size_t)t0 * 4096;
    gx0 = x0[ob0]; gx1 = x0[ob1]; gx2 = x0[ob2]; gx3 = x0[ob3];
  }
  __syncthreads();

#define STEP(RD, WR, TCUR, TNXT)                                                   \
  {                                                                                \
    short8 af0 = *(const short8*)((const char*)(RD) + aoff[0]);                    \
    short8 af1 = *(const short8*)((const char*)(RD) + aoff[1]);                    \
    short8 af2 = *(const short8*)((const char*)(RD) + aoff[2]);                    \
    short8 af3 = *(const short8*)((const char*)(RD) + aoff[3]);                    \
    f32x4 acc0 = __builtin_amdgcn_mfma_f32_16x16x32_bf16(af0, whf[0][0], gx2f(gx0), 0, 0, 0); \
    f32x4 acc1 = __builtin_amdgcn_mfma_f32_16x16x32_bf16(af0, whf[1][0], gx2f(gx1), 0, 0, 0); \
    f32x4 acc2 = __builtin_amdgcn_mfma_f32_16x16x32_bf16(af0, whf[2][0], gx2f(gx2), 0, 0, 0); \
    f32x4 acc3 = __builtin_amdgcn_mfma_f32_16x16x32_bf16(af0, whf[3][0], gx2f(gx3), 0, 0, 0); \
    {                                                                              \
      const gxT* xn = xpg + (size_t)(TNXT) * 4096;                                 \
      gx0 = xn[ob0]; gx1 = xn[ob1]; gx2 = xn[ob2]; gx3 = xn[ob3];                  \
    }                                                                              \
    acc0 = __builtin_amdgcn_mfma_f32_16x16x32_bf16(af1, whf[0][1], acc0, 0, 0, 0); \
    acc1 = __builtin_amdgcn_mfma_f32_16x16x32_bf16(af1, whf[1][1], acc1, 0, 0, 0); \
    acc2 = __builtin_amdgcn_mfma_f32_16x16x32_bf16(af1, whf[2][1], acc2, 0, 0, 0); \
    acc3 = __builtin_amdgcn_mfma_f32_16x16x32_bf16(af1, whf[3][1], acc3, 0, 0, 0); \
    acc0 = __builtin_amdgcn_mfma_f32_16x16x32_bf16(af2, whf[0][2], acc0, 0, 0, 0); \
    acc1 = __builtin_amdgcn_mfma_f32_16x16x32_bf16(af2, whf[1][2], acc1, 0, 0, 0); \
    acc2 = __builtin_amdgcn_mfma_f32_16x16x32_bf16(af2, whf[2][2], acc2, 0, 0, 0); \
    acc3 = __builtin_amdgcn_mfma_f32_16x16x32_bf16(af2, whf[3][2], acc3, 0, 0, 0); \
    acc0 = __builtin_amdgcn_mfma_f32_16x16x32_bf16(af3, whf[0][3], acc0, 0, 0, 0); \
    acc1 = __builtin_amdgcn_mfma_f32_16x16x32_bf16(af3, whf[1][3], acc1, 0, 0, 0); \
    acc2 = __builtin_amdgcn_mfma_f32_16x16x32_bf16(af3, whf[2][3], acc2, 0, 0, 0); \
    acc3 = __builtin_amdgcn_mfma_f32_16x16x32_bf16(af3, whf[3][3], acc3, 0, 0, 0); \
    unsigned short* op = out0 + (size_t)(TCUR) * 8192 + obout;                     \
    _Pragma("unroll") for (int r = 0; r < 4; ++r) {                                \
      float ei = __builtin_amdgcn_exp2f(acc0[r]);                                  \
      float ef = __builtin_amdgcn_exp2f(acc1[r]);                                  \
      float eg = __builtin_amdgcn_exp2f(acc2[r]);                                  \
      float eo = __builtin_amdgcn_exp2f(acc3[r]);                                  \
      float ig = __builtin_amdgcn_rcpf(1.0f + ei);                                 \
      float fg = __builtin_amdgcn_rcpf(1.0f + ef);                                 \
      float gg = 2.0f * __builtin_amdgcn_rcpf(1.0f + eg) - 1.0f;                   \
      float og = __builtin_amdgcn_rcpf(1.0f + eo);                                 \
      float cn = __builtin_fmaf(fg, cst[r], ig * gg);                              \
      cst[r] = cn;                                                                 \
      float et = __builtin_amdgcn_exp2f(M2L2E * cn);                               \
      float th = 2.0f * __builtin_amdgcn_rcpf(1.0f + et) - 1.0f;                   \
      float h = og * th;                                                           \
      unsigned short hb = f2bf(h);                                                 \
      *(unsigned short*)((char*)(WR) + woff[r]) = hb;                              \
      if (LAYER == 0) op[(size_t)r * 256] = hb;                                    \
      else dout[dpb + (size_t)(TCUR) * 256 + (size_t)r * ((size_t)T * 256)] = h;   \
    }                                                                              \
    asm volatile("s_waitcnt lgkmcnt(0)" ::: "memory");                             \
    __builtin_amdgcn_s_barrier();                                                  \
    asm volatile("" ::: "memory");                                                 \
  }

  int t = t0;
  for (int s = 0; s < T; s += 2) {
    int t1 = t + ts;
    STEP(hA, hB, t, t1);
    int t2n = (s + 2 < T) ? (t1 + ts) : t1;
    STEP(hB, hA, t1, t2n);
    t = t1 + ts;
  }
#undef STEP

  if constexpr (LAYER == 1) {
#pragma unroll
    for (int r = 0; r < 4; ++r)
      dout[XOUT + (size_t)(b0 + r) * 256 + dir * 128 + col] = cst[r];
  }
}

// ---------------------------------------------------------------------------
extern "C" void kernel_launch(void* const* d_in, const int* in_sizes, int n_in,
                              void* d_out, int out_size, void* d_ws, size_t ws_size,
                              hipStream_t stream) {
  const float* x    = (const float*)d_in[0];
  const float* wxf0 = (const float*)d_in[1];
  const float* whf0 = (const float*)d_in[2];
  const float* wxb0 = (const float*)d_in[3];
  const float* whb0 = (const float*)d_in[4];
  const float* wxf1 = (const float*)d_in[5];
  const float* whf1 = (const float*)d_in[6];
  const float* wxb1 = (const float*)d_in[7];
  const float* whb1 = (const float*)d_in[8];
  const float* bf0  = (const float*)d_in[9];
  const float* bb0  = (const float*)d_in[10];
  const float* bf1  = (const float*)d_in[11];
  const float* bb1  = (const float*)d_in[12];
  float* dout = (float*)d_out;

  // ws: [xp][out0 bf16][sw0][sw1][swh]
  const size_t needF32 = 268435456u + 33554432u + 262144u + 524288u + 524288u;
  bool xpf32 = ws_size >= needF32;
  size_t xpBytes = xpf32 ? 268435456u : 134217728u;
  unsigned char* ws = (unsigned char*)d_ws;
  void* xp = (void*)ws;
  unsigned short* out0 = (unsigned short*)(ws + xpBytes);
  unsigned short* sw0  = (unsigned short*)(ws + xpBytes + 33554432u);
  unsigned short* sw1  = sw0 + 2 * 65536;
  unsigned short* swh  = sw1 + 2 * 131072;

  prep_wx<<<1536, 256, 0, stream>>>(wxf0, wxb0, wxf1, wxb1, sw0, sw1);
  prep_wh<<<1024, 256, 0, stream>>>(whf0, whb0, whf1, whb1, swh);

  if (xpf32) {
    input_proj<0, true><<<dim3(2048, 2), 256, 0, stream>>>(x, nullptr, sw0, bf0, bb0, xp);
    lstm_scan<0, true><<<4, 512, 0, stream>>>(xp, swh, out0, nullptr);
    input_proj<1, true><<<dim3(2048, 2), 256, 0, stream>>>(nullptr, out0, sw1, bf1, bb1, xp);
    lstm_scan<1, true><<<4, 512, 0, stream>>>(xp, swh, out0, dout);
  } else {
    input_proj<0, false><<<dim3(2048, 2), 256, 0, stream>>>(x, nullptr, sw0, bf0, bb0, xp);
    lstm_scan<0, false><<<4, 512, 0, stream>>>(xp, swh, out0, nullptr);
    input_proj<1, false><<<dim3(2048, 2), 256, 0, stream>>>(nullptr, out0, sw1, bf1, bb1, xp);
    lstm_scan<1, false><<<4, 512, 0, stream>>>(xp, swh, out0, dout);
  }
}

// Round 4
// 3140.563 us; speedup vs baseline: 2.5606x; 1.0832x over previous
//
#include <hip/hip_runtime.h>
#include <hip/hip_bf16.h>
#include <stdint.h>
#include <type_traits>

// Bidirectional 2-layer LSTM, B=32, T=2048, F=H=128, G=4H=512.
// prep (Wx,Wh -> scaled bf16 frags) -> proj L0 -> scan L0 (4 WGs: dir x bhalf)
// -> proj L1 -> scan L1. Gate pre-activations are pre-scaled by -log2e
// (i,f,o) / -2log2e (g) so sigmoid = rcp(1+exp2(y)).
// Activation uses common-denominator form: 7 trans ops/elem instead of 10.

#define DEVINL __device__ __forceinline__

typedef __attribute__((ext_vector_type(8))) short short8;
typedef __attribute__((ext_vector_type(4))) float f32x4;

static constexpr int T = 2048;
static constexpr size_t XOUT = (size_t)32 * T * 256;
static constexpr float L2E = 1.4426950408889634f;
static constexpr float M2L2E = -2.8853900817779268f;

DEVINL unsigned short f2bf(float f) {
  unsigned int u = __float_as_uint(f);
  u += 0x7FFFu + ((u >> 16) & 1u);  // RNE
  return (unsigned short)(u >> 16);
}
DEVINL float gate_scale(int g) { return (g == 2) ? M2L2E : -L2E; }

// ---------------------------------------------------------------------------
// prep_wx: Wx (f32 [K][512]) -> scaled bf16 B-frags [dir][ng(32)][ks][lane][e8]
// ---------------------------------------------------------------------------
__global__ __launch_bounds__(256) void prep_wx(const float* wxf0, const float* wxb0,
                                               const float* wxf1, const float* wxb1,
                                               unsigned short* sw0, unsigned short* sw1) {
  int idx = blockIdx.x * 256 + threadIdx.x;
  if (idx < 2 * 65536) {                       // layer 0, KS=4
    int d = idx >> 16;
    int local = idx & 65535;
    const float* w = d ? wxb0 : wxf0;
    int e = local & 7, lane = (local >> 3) & 63, ks = (local >> 9) & 3, ng = local >> 11;
    int col = ng * 16 + (lane & 15);
    int k = ks * 32 + ((lane >> 4) << 3) + e;
    sw0[idx] = f2bf(w[k * 512 + col] * gate_scale(ng >> 3));
  } else {                                     // layer 1, KS=8
    int j = idx - 2 * 65536;
    if (j < 2 * 131072) {
      int d = j >> 17;
      int local = j & 131071;
      const float* w = d ? wxb1 : wxf1;
      int e = local & 7, lane = (local >> 3) & 63, ks = (local >> 9) & 7, ng = local >> 12;
      int col = ng * 16 + (lane & 15);
      int k = ks * 32 + ((lane >> 4) << 3) + e;
      sw1[j] = f2bf(w[k * 512 + col] * gate_scale(ng >> 3));
    }
  }
}

// ---------------------------------------------------------------------------
// prep_wh: Wh (f32 [128][512]) -> scaled bf16 frags, contiguous per (wave):
// idx bits: e(0-2) lane(3-8) wid(9-11) ks(12-13) g(14-15) dir(16) layer(17)
// ---------------------------------------------------------------------------
__global__ __launch_bounds__(256) void prep_wh(const float* whf0, const float* whb0,
                                               const float* whf1, const float* whb1,
                                               unsigned short* swh) {
  int idx = blockIdx.x * 256 + threadIdx.x;
  if (idx >= 262144) return;
  int e = idx & 7, lane = (idx >> 3) & 63, wid = (idx >> 9) & 7;
  int ks = (idx >> 12) & 3, g = (idx >> 14) & 3, dir = (idx >> 16) & 1, layer = (idx >> 17) & 1;
  const float* w = layer ? (dir ? whb1 : whf1) : (dir ? whb0 : whf0);
  int col = g * 128 + wid * 16 + (lane & 15);
  int k = ks * 32 + ((lane >> 4) << 3) + e;
  swh[idx] = f2bf(w[k * 512 + col] * gate_scale(g));
}

// ---------------------------------------------------------------------------
// input_proj: xp[dir][t][32x512] = A(t) @ Wx_scaled + b_scaled, D-frag order:
// f32x4 index = t*4096 + (ng*2+mt)*64 + lane
// ---------------------------------------------------------------------------
template <int LAYER, bool XPF32>
__global__ __launch_bounds__(256) void input_proj(const float* x, const unsigned short* a_bf,
                                                  const unsigned short* wsw,
                                                  const float* bias_f, const float* bias_b,
                                                  void* xp_out) {
  constexpr int KS = (LAYER == 0) ? 4 : 8;
  int t = blockIdx.x, dir = blockIdx.y;
  int wid = threadIdx.x >> 6, lane = threadIdx.x & 63;
  const unsigned short* wbase = wsw + (size_t)dir * (32 * KS * 64 * 8);
  const float* bias = dir ? bias_b : bias_f;

  short8 afrag[2][KS];
#pragma unroll
  for (int mt = 0; mt < 2; ++mt) {
#pragma unroll
    for (int ks = 0; ks < KS; ++ks) {
      int m = (lane & 15) + mt * 16;
      int kk = ks * 32 + ((lane >> 4) << 3);
      if constexpr (LAYER == 0) {
        const float* ap = x + (size_t)m * (T * 128) + (size_t)t * 128 + kk;
        float4 lo = *(const float4*)ap;
        float4 hi = *(const float4*)(ap + 4);
        short8 s;
        s[0] = (short)f2bf(lo.x); s[1] = (short)f2bf(lo.y);
        s[2] = (short)f2bf(lo.z); s[3] = (short)f2bf(lo.w);
        s[4] = (short)f2bf(hi.x); s[5] = (short)f2bf(hi.y);
        s[6] = (short)f2bf(hi.z); s[7] = (short)f2bf(hi.w);
        afrag[mt][ks] = s;
      } else {
        afrag[mt][ks] = *(const short8*)(a_bf + ((size_t)t * 32 + m) * 256 + kk);
      }
    }
  }

#pragma unroll
  for (int ngi = 0; ngi < 8; ++ngi) {
    int ng = wid * 8 + ngi;
    f32x4 acc0 = {0.f, 0.f, 0.f, 0.f};
    f32x4 acc1 = {0.f, 0.f, 0.f, 0.f};
#pragma unroll
    for (int ks = 0; ks < KS; ++ks) {
      short8 b = *(const short8*)(wbase + ((size_t)(ng * KS + ks) * 64 + lane) * 8);
      acc0 = __builtin_amdgcn_mfma_f32_16x16x32_bf16(afrag[0][ks], b, acc0, 0, 0, 0);
      acc1 = __builtin_amdgcn_mfma_f32_16x16x32_bf16(afrag[1][ks], b, acc1, 0, 0, 0);
    }
    float bs = bias[ng * 16 + (lane & 15)] * gate_scale(ng >> 3);
#pragma unroll
    for (int mt = 0; mt < 2; ++mt) {
      f32x4 v = (mt == 0) ? acc0 : acc1;
      v[0] += bs; v[1] += bs; v[2] += bs; v[3] += bs;
      size_t idx4 = (size_t)t * 4096 + ((size_t)ng * 2 + mt) * 64 + lane;
      if constexpr (XPF32) {
        ((f32x4*)xp_out)[(size_t)dir * 8388608 + idx4] = v;
      } else {
        unsigned int lo = (unsigned)f2bf(v[0]) | ((unsigned)f2bf(v[1]) << 16);
        unsigned int hi = (unsigned)f2bf(v[2]) | ((unsigned)f2bf(v[3]) << 16);
        uint2 u; u.x = lo; u.y = hi;
        *(uint2*)((unsigned short*)xp_out + (size_t)dir * 33554432 + idx4 * 4) = u;
      }
    }
  }
}

// ---------------------------------------------------------------------------
// lstm_scan: 4 persistent WGs (blockIdx = dir*2 + batch-half), 8 waves each.
// Wave wid owns 16 hidden cols (all 4 gates). Wh in regs; h double-buffered
// in LDS (XOR-swizzled); gx prefetched into registers; c in regs.
// One lgkm-only barrier per step. 7-trans activation.
// ---------------------------------------------------------------------------
DEVINL f32x4 gx2f(f32x4 v) { return v; }
DEVINL f32x4 gx2f(uint2 u) {
  f32x4 v;
  v[0] = __uint_as_float(u.x << 16);
  v[1] = __uint_as_float(u.x & 0xFFFF0000u);
  v[2] = __uint_as_float(u.y << 16);
  v[3] = __uint_as_float(u.y & 0xFFFF0000u);
  return v;
}

template <int LAYER, bool XPF32>
__global__ __launch_bounds__(512, 2) void lstm_scan(const void* xp, const unsigned short* swh,
                                                    unsigned short* out0, float* dout) {
  using gxT = typename std::conditional<XPF32, f32x4, uint2>::type;
  int dir = blockIdx.x >> 1;
  int mh = blockIdx.x & 1;
  int wid = threadIdx.x >> 6, lane = threadIdx.x & 63;
  int m = lane & 15;
  int khi = (lane >> 4) << 3;

  __shared__ __align__(16) unsigned short hA[2048];  // 16 rows x 128 cols bf16
  __shared__ __align__(16) unsigned short hB[2048];

  // Wh fragments (pre-scaled, pre-fragged): 16 contiguous b128 loads
  const unsigned short* whbase = swh + (size_t)LAYER * 131072 + (size_t)dir * 65536;
  short8 whf[4][4];
#pragma unroll
  for (int g = 0; g < 4; ++g)
#pragma unroll
    for (int ks = 0; ks < 4; ++ks)
      whf[g][ks] = *(const short8*)(whbase + g * 16384 + ks * 4096 + wid * 512 + lane * 8);

  for (int i = threadIdx.x; i < 1024; i += 512) {
    ((unsigned int*)hA)[i] = 0u;
    ((unsigned int*)hB)[i] = 0u;
  }

  // LDS read offsets (A-frags of h), swizzled
  int aoff[4];
#pragma unroll
  for (int ks = 0; ks < 4; ++ks) {
    int kb = ks * 64 + khi * 2;
    aoff[ks] = m * 256 + (kb ^ ((m & 7) << 4));
  }
  // LDS write offsets for h
  int col = wid * 16 + m;
  int b0r = (lane >> 4) << 2;
  int woff[4];
#pragma unroll
  for (int r = 0; r < 4; ++r) {
    int row = b0r + r;
    woff[r] = row * 256 + ((col * 2) ^ ((row & 7) << 4));
  }

  // gx addressing (xp is in D-frag order)
  const gxT* xpg = (const gxT*)((const unsigned char*)xp +
                                (size_t)dir * (XPF32 ? 134217728u : 67108864u));
  int ob0 = ((0 * 8 + wid) * 2 + mh) * 64 + lane;
  int ob1 = ((1 * 8 + wid) * 2 + mh) * 64 + lane;
  int ob2 = ((2 * 8 + wid) * 2 + mh) * 64 + lane;
  int ob3 = ((3 * 8 + wid) * 2 + mh) * 64 + lane;

  int b0 = mh * 16 + b0r;                              // global batch row base
  int obout = b0 * 256 + dir * 128 + col;              // lane elem offset in out0 step
  unsigned int dlo[4];                                  // lane byte offsets in dout
#pragma unroll
  for (int r = 0; r < 4; ++r)
    dlo[r] = (unsigned int)((((size_t)(b0 + r) * T) * 256 + dir * 128 + col) * 4);

  f32x4 cst = {0.f, 0.f, 0.f, 0.f};

  int t0 = dir ? (T - 1) : 0;
  int ts = dir ? -1 : 1;

  const gxT* gxp = xpg + (size_t)t0 * 4096;
  unsigned short* outp = out0 + (size_t)t0 * 8192;     // L0 running base (t*32*256)
  char* dp = (char*)dout + (size_t)t0 * 1024;          // L1 running base (t*256*4B)
  const ptrdiff_t GXS = (ptrdiff_t)ts * 4096;
  const ptrdiff_t OUS = (ptrdiff_t)ts * 8192;
  const ptrdiff_t DPS = (ptrdiff_t)ts * 1024;

  gxT gx0 = gxp[ob0], gx1 = gxp[ob1], gx2 = gxp[ob2], gx3 = gxp[ob3];
  __syncthreads();

#define STEP(RD, WR)                                                               \
  {                                                                                \
    short8 af0 = *(const short8*)((const char*)(RD) + aoff[0]);                    \
    short8 af1 = *(const short8*)((const char*)(RD) + aoff[1]);                    \
    short8 af2 = *(const short8*)((const char*)(RD) + aoff[2]);                    \
    short8 af3 = *(const short8*)((const char*)(RD) + aoff[3]);                    \
    f32x4 acc0 = __builtin_amdgcn_mfma_f32_16x16x32_bf16(af0, whf[0][0], gx2f(gx0), 0, 0, 0); \
    f32x4 acc1 = __builtin_amdgcn_mfma_f32_16x16x32_bf16(af0, whf[1][0], gx2f(gx1), 0, 0, 0); \
    f32x4 acc2 = __builtin_amdgcn_mfma_f32_16x16x32_bf16(af0, whf[2][0], gx2f(gx2), 0, 0, 0); \
    f32x4 acc3 = __builtin_amdgcn_mfma_f32_16x16x32_bf16(af0, whf[3][0], gx2f(gx3), 0, 0, 0); \
    gxp += GXS;                                                                    \
    gx0 = gxp[ob0]; gx1 = gxp[ob1]; gx2 = gxp[ob2]; gx3 = gxp[ob3];                \
    acc0 = __builtin_amdgcn_mfma_f32_16x16x32_bf16(af1, whf[0][1], acc0, 0, 0, 0); \
    acc1 = __builtin_amdgcn_mfma_f32_16x16x32_bf16(af1, whf[1][1], acc1, 0, 0, 0); \
    acc2 = __builtin_amdgcn_mfma_f32_16x16x32_bf16(af1, whf[2][1], acc2, 0, 0, 0); \
    acc3 = __builtin_amdgcn_mfma_f32_16x16x32_bf16(af1, whf[3][1], acc3, 0, 0, 0); \
    acc0 = __builtin_amdgcn_mfma_f32_16x16x32_bf16(af2, whf[0][2], acc0, 0, 0, 0); \
    acc1 = __builtin_amdgcn_mfma_f32_16x16x32_bf16(af2, whf[1][2], acc1, 0, 0, 0); \
    acc2 = __builtin_amdgcn_mfma_f32_16x16x32_bf16(af2, whf[2][2], acc2, 0, 0, 0); \
    acc3 = __builtin_amdgcn_mfma_f32_16x16x32_bf16(af2, whf[3][2], acc3, 0, 0, 0); \
    acc0 = __builtin_amdgcn_mfma_f32_16x16x32_bf16(af3, whf[0][3], acc0, 0, 0, 0); \
    acc1 = __builtin_amdgcn_mfma_f32_16x16x32_bf16(af3, whf[1][3], acc1, 0, 0, 0); \
    acc2 = __builtin_amdgcn_mfma_f32_16x16x32_bf16(af3, whf[2][3], acc2, 0, 0, 0); \
    acc3 = __builtin_amdgcn_mfma_f32_16x16x32_bf16(af3, whf[3][3], acc3, 0, 0, 0); \
    float hr[4];                                                                   \
    _Pragma("unroll") for (int r = 0; r < 4; ++r) {                                \
      float ei = __builtin_amdgcn_exp2f(acc0[r]);                                  \
      float efv = __builtin_amdgcn_exp2f(acc1[r]);                                 \
      float eg = __builtin_amdgcn_exp2f(acc2[r]);                                  \
      float eo = __builtin_amdgcn_exp2f(acc3[r]);                                  \
      float ai = 1.0f + ei, av = 1.0f + efv, ag = 1.0f + eg, sg = 1.0f - eg;       \
      float p = ai * ag;                                                           \
      float num = __builtin_fmaf(cst[r], p, sg * av);                              \
      float rd = __builtin_amdgcn_rcpf(av * p);                                    \
      float cn = num * rd;                                                         \
      cst[r] = cn;                                                                 \
      float ec = __builtin_amdgcn_exp2f(M2L2E * cn);                               \
      float ao = 1.0f + eo, ac = 1.0f + ec, sc = 1.0f - ec;                        \
      float rd2 = __builtin_amdgcn_rcpf(ao * ac);                                  \
      hr[r] = sc * rd2;                                                            \
    }                                                                              \
    unsigned int pk01, pk23;                                                       \
    asm("v_cvt_pk_bf16_f32 %0, %1, %2" : "=v"(pk01) : "v"(hr[0]), "v"(hr[1]));     \
    asm("v_cvt_pk_bf16_f32 %0, %1, %2" : "=v"(pk23) : "v"(hr[2]), "v"(hr[3]));     \
    unsigned short h0 = (unsigned short)pk01, h1 = (unsigned short)(pk01 >> 16);   \
    unsigned short h2 = (unsigned short)pk23, h3 = (unsigned short)(pk23 >> 16);   \
    *(unsigned short*)((char*)(WR) + woff[0]) = h0;                                \
    *(unsigned short*)((char*)(WR) + woff[1]) = h1;                                \
    *(unsigned short*)((char*)(WR) + woff[2]) = h2;                                \
    *(unsigned short*)((char*)(WR) + woff[3]) = h3;                                \
    if (LAYER == 0) {                                                              \
      outp[obout]       = h0;                                                      \
      outp[obout + 256] = h1;                                                      \
      outp[obout + 512] = h2;                                                      \
      outp[obout + 768] = h3;                                                      \
      outp += OUS;                                                                 \
    } else {                                                                       \
      *(float*)(dp + dlo[0]) = hr[0];                                              \
      *(float*)(dp + dlo[1]) = hr[1];                                              \
      *(float*)(dp + dlo[2]) = hr[2];                                              \
      *(float*)(dp + dlo[3]) = hr[3];                                              \
      dp += DPS;                                                                   \
    }                                                                              \
    asm volatile("s_waitcnt lgkmcnt(0)" ::: "memory");                             \
    __builtin_amdgcn_s_barrier();                                                  \
    asm volatile("" ::: "memory");                                                 \
  }

  for (int s = 0; s < T; s += 2) {
    STEP(hA, hB);
    STEP(hB, hA);
  }
#undef STEP

  if constexpr (LAYER == 1) {
#pragma unroll
    for (int r = 0; r < 4; ++r)
      dout[XOUT + (size_t)(b0 + r) * 256 + dir * 128 + col] = cst[r];
  }
}

// ---------------------------------------------------------------------------
extern "C" void kernel_launch(void* const* d_in, const int* in_sizes, int n_in,
                              void* d_out, int out_size, void* d_ws, size_t ws_size,
                              hipStream_t stream) {
  const float* x    = (const float*)d_in[0];
  const float* wxf0 = (const float*)d_in[1];
  const float* whf0 = (const float*)d_in[2];
  const float* wxb0 = (const float*)d_in[3];
  const float* whb0 = (const float*)d_in[4];
  const float* wxf1 = (const float*)d_in[5];
  const float* whf1 = (const float*)d_in[6];
  const float* wxb1 = (const float*)d_in[7];
  const float* whb1 = (const float*)d_in[8];
  const float* bf0  = (const float*)d_in[9];
  const float* bb0  = (const float*)d_in[10];
  const float* bf1  = (const float*)d_in[11];
  const float* bb1  = (const float*)d_in[12];
  float* dout = (float*)d_out;

  // ws: [xp][out0 bf16][sw0][sw1][swh]
  const size_t needF32 = 268435456u + 33554432u + 262144u + 524288u + 524288u;
  bool xpf32 = ws_size >= needF32;
  size_t xpBytes = xpf32 ? 268435456u : 134217728u;
  unsigned char* ws = (unsigned char*)d_ws;
  void* xp = (void*)ws;
  unsigned short* out0 = (unsigned short*)(ws + xpBytes);
  unsigned short* sw0  = (unsigned short*)(ws + xpBytes + 33554432u);
  unsigned short* sw1  = sw0 + 2 * 65536;
  unsigned short* swh  = sw1 + 2 * 131072;

  prep_wx<<<1536, 256, 0, stream>>>(wxf0, wxb0, wxf1, wxb1, sw0, sw1);
  prep_wh<<<1024, 256, 0, stream>>>(whf0, whb0, whf1, whb1, swh);

  if (xpf32) {
    input_proj<0, true><<<dim3(2048, 2), 256, 0, stream>>>(x, nullptr, sw0, bf0, bb0, xp);
    lstm_scan<0, true><<<4, 512, 0, stream>>>(xp, swh, out0, nullptr);
    input_proj<1, true><<<dim3(2048, 2), 256, 0, stream>>>(nullptr, out0, sw1, bf1, bb1, xp);
    lstm_scan<1, true><<<4, 512, 0, stream>>>(xp, swh, out0, dout);
  } else {
    input_proj<0, false><<<dim3(2048, 2), 256, 0, stream>>>(x, nullptr, sw0, bf0, bb0, xp);
    lstm_scan<0, false><<<4, 512, 0, stream>>>(xp, swh, out0, nullptr);
    input_proj<1, false><<<dim3(2048, 2), 256, 0, stream>>>(nullptr, out0, sw1, bf1, bb1, xp);
    lstm_scan<1, false><<<4, 512, 0, stream>>>(xp, swh, out0, dout);
  }
}

// Round 5
// 2395.079 us; speedup vs baseline: 3.3576x; 1.3113x over previous
//
#include <hip/hip_runtime.h>
#include <hip/hip_bf16.h>
#include <stdint.h>
#include <type_traits>

// Bidirectional 2-layer LSTM, B=32, T=2048, F=H=128, G=4H=512.
// prep (Wx,Wh -> scaled bf16 frags) -> proj L0 -> scan L0 (8 WGs: dir x bquarter)
// -> proj L1 -> scan L1. Gate pre-activations pre-scaled by -log2e (i,f,o) /
// -2log2e (g) so sigmoid = rcp(1+exp2(y)). 7-trans common-denominator activation.
// Scan uses duplicate-row MFMA tiles (8 batch rows copied into rows 8-15) so all
// 64 lanes hold exactly 2 valid state elems -> wave-level trans work halves.

#define DEVINL __device__ __forceinline__

typedef __attribute__((ext_vector_type(8))) short short8;
typedef __attribute__((ext_vector_type(4))) float f32x4;

static constexpr int T = 2048;
static constexpr size_t XOUT = (size_t)32 * T * 256;
static constexpr float L2E = 1.4426950408889634f;
static constexpr float M2L2E = -2.8853900817779268f;

DEVINL unsigned short f2bf(float f) {
  unsigned int u = __float_as_uint(f);
  u += 0x7FFFu + ((u >> 16) & 1u);  // RNE
  return (unsigned short)(u >> 16);
}
DEVINL float gate_scale(int g) { return (g == 2) ? M2L2E : -L2E; }

// ---------------------------------------------------------------------------
// prep_wx: Wx (f32 [K][512]) -> scaled bf16 B-frags [dir][ng(32)][ks][lane][e8]
// ---------------------------------------------------------------------------
__global__ __launch_bounds__(256) void prep_wx(const float* wxf0, const float* wxb0,
                                               const float* wxf1, const float* wxb1,
                                               unsigned short* sw0, unsigned short* sw1) {
  int idx = blockIdx.x * 256 + threadIdx.x;
  if (idx < 2 * 65536) {                       // layer 0, KS=4
    int d = idx >> 16;
    int local = idx & 65535;
    const float* w = d ? wxb0 : wxf0;
    int e = local & 7, lane = (local >> 3) & 63, ks = (local >> 9) & 3, ng = local >> 11;
    int col = ng * 16 + (lane & 15);
    int k = ks * 32 + ((lane >> 4) << 3) + e;
    sw0[idx] = f2bf(w[k * 512 + col] * gate_scale(ng >> 3));
  } else {                                     // layer 1, KS=8
    int j = idx - 2 * 65536;
    if (j < 2 * 131072) {
      int d = j >> 17;
      int local = j & 131071;
      const float* w = d ? wxb1 : wxf1;
      int e = local & 7, lane = (local >> 3) & 63, ks = (local >> 9) & 7, ng = local >> 12;
      int col = ng * 16 + (lane & 15);
      int k = ks * 32 + ((lane >> 4) << 3) + e;
      sw1[j] = f2bf(w[k * 512 + col] * gate_scale(ng >> 3));
    }
  }
}

// ---------------------------------------------------------------------------
// prep_wh: Wh (f32 [128][512]) -> scaled bf16 frags, contiguous per wave:
// idx bits: e(0-2) lane(3-8) wid(9-11) ks(12-13) g(14-15) dir(16) layer(17)
// ---------------------------------------------------------------------------
__global__ __launch_bounds__(256) void prep_wh(const float* whf0, const float* whb0,
                                               const float* whf1, const float* whb1,
                                               unsigned short* swh) {
  int idx = blockIdx.x * 256 + threadIdx.x;
  if (idx >= 262144) return;
  int e = idx & 7, lane = (idx >> 3) & 63, wid = (idx >> 9) & 7;
  int ks = (idx >> 12) & 3, g = (idx >> 14) & 3, dir = (idx >> 16) & 1, layer = (idx >> 17) & 1;
  const float* w = layer ? (dir ? whb1 : whf1) : (dir ? whb0 : whf0);
  int col = g * 128 + wid * 16 + (lane & 15);
  int k = ks * 32 + ((lane >> 4) << 3) + e;
  swh[idx] = f2bf(w[k * 512 + col] * gate_scale(g));
}

// ---------------------------------------------------------------------------
// input_proj: xp[dir][t][...] = A(t) @ Wx_scaled + b_scaled, stored COMPACT:
// unit index (f32x2 / packed-dword) = t*8192 + ((q*4+g)*8 + wd)*64 + L*16 + c15
// where q=batch quarter, g=gate, wd=col>>4, L encodes the row pair, c15=col&15.
// ---------------------------------------------------------------------------
template <int LAYER, bool XPF32>
__global__ __launch_bounds__(256) void input_proj(const float* x, const unsigned short* a_bf,
                                                  const unsigned short* wsw,
                                                  const float* bias_f, const float* bias_b,
                                                  void* xp_out) {
  constexpr int KS = (LAYER == 0) ? 4 : 8;
  int t = blockIdx.x, dir = blockIdx.y;
  int wid = threadIdx.x >> 6, lane = threadIdx.x & 63;
  int p = lane >> 4, c15 = lane & 15;
  const unsigned short* wbase = wsw + (size_t)dir * (32 * KS * 64 * 8);
  const float* bias = dir ? bias_b : bias_f;

  short8 afrag[2][KS];
#pragma unroll
  for (int mt = 0; mt < 2; ++mt) {
#pragma unroll
    for (int ks = 0; ks < KS; ++ks) {
      int m = c15 + mt * 16;
      int kk = ks * 32 + (p << 3);
      if constexpr (LAYER == 0) {
        const float* ap = x + (size_t)m * (T * 128) + (size_t)t * 128 + kk;
        float4 lov = *(const float4*)ap;
        float4 hiv = *(const float4*)(ap + 4);
        short8 s;
        s[0] = (short)f2bf(lov.x); s[1] = (short)f2bf(lov.y);
        s[2] = (short)f2bf(lov.z); s[3] = (short)f2bf(lov.w);
        s[4] = (short)f2bf(hiv.x); s[5] = (short)f2bf(hiv.y);
        s[6] = (short)f2bf(hiv.z); s[7] = (short)f2bf(hiv.w);
        afrag[mt][ks] = s;
      } else {
        afrag[mt][ks] = *(const short8*)(a_bf + ((size_t)t * 32 + m) * 256 + kk);
      }
    }
  }

  size_t dirbase = (size_t)dir * 16777216u;   // units (f32x2 or dword)

#pragma unroll
  for (int ngi = 0; ngi < 8; ++ngi) {
    int ng = wid * 8 + ngi;
    f32x4 acc0 = {0.f, 0.f, 0.f, 0.f};
    f32x4 acc1 = {0.f, 0.f, 0.f, 0.f};
#pragma unroll
    for (int ks = 0; ks < KS; ++ks) {
      short8 b = *(const short8*)(wbase + ((size_t)(ng * KS + ks) * 64 + lane) * 8);
      acc0 = __builtin_amdgcn_mfma_f32_16x16x32_bf16(afrag[0][ks], b, acc0, 0, 0, 0);
      acc1 = __builtin_amdgcn_mfma_f32_16x16x32_bf16(afrag[1][ks], b, acc1, 0, 0, 0);
    }
    float bs = bias[ng * 16 + c15] * gate_scale(ng >> 3);
    int g = ng >> 3, wd = ng & 7;
#pragma unroll
    for (int mt = 0; mt < 2; ++mt) {
      f32x4 v = (mt == 0) ? acc0 : acc1;
      v[0] += bs; v[1] += bs; v[2] += bs; v[3] += bs;
      int q = mt * 2 + (p >> 1);
      size_t idx = (size_t)t * 8192 + (size_t)(((q * 4 + g) * 8 + wd) * 64 + (p & 1) * 16 + c15);
      if constexpr (XPF32) {
        float2 a; a.x = v[0]; a.y = v[1];
        float2 b2; b2.x = v[2]; b2.y = v[3];
        ((float2*)xp_out)[dirbase + idx] = a;
        ((float2*)xp_out)[dirbase + idx + 32] = b2;
      } else {
        unsigned int pa = (unsigned)f2bf(v[0]) | ((unsigned)f2bf(v[1]) << 16);
        unsigned int pb = (unsigned)f2bf(v[2]) | ((unsigned)f2bf(v[3]) << 16);
        ((unsigned int*)xp_out)[dirbase + idx] = pa;
        ((unsigned int*)xp_out)[dirbase + idx + 32] = pb;
      }
    }
  }
}

// ---------------------------------------------------------------------------
// lstm_scan: 8 persistent WGs (blockIdx = dir*4 + quarter), 8 waves each.
// Wave wid owns 16 h-cols (all 4 gates) for 8 batch rows. Wh in regs; h
// double-buffered in LDS (8x128 bf16, XOR-swizzled, rows duplicated on read);
// gx in regs (compact layout); c in regs (2/thread). 1 lgkm barrier/step.
// ---------------------------------------------------------------------------
DEVINL float2 gxpair(float2 v) { return v; }
DEVINL float2 gxpair(unsigned int u) {
  float2 v;
  v.x = __uint_as_float(u << 16);
  v.y = __uint_as_float(u & 0xFFFF0000u);
  return v;
}

DEVINL float actstep(float pi, float pf, float pg, float po, float& c) {
  float ei = __builtin_amdgcn_exp2f(pi);
  float ef = __builtin_amdgcn_exp2f(pf);
  float eg = __builtin_amdgcn_exp2f(pg);
  float eo = __builtin_amdgcn_exp2f(po);
  float ai = 1.0f + ei, av = 1.0f + ef, ag = 1.0f + eg, sg = 1.0f - eg;
  float pp = ai * ag;
  float num = __builtin_fmaf(c, pp, sg * av);
  float rd = __builtin_amdgcn_rcpf(av * pp);
  float cn = num * rd;
  c = cn;
  float ec = __builtin_amdgcn_exp2f(M2L2E * cn);
  float ao = 1.0f + eo, ac = 1.0f + ec, sc = 1.0f - ec;
  float rd2 = __builtin_amdgcn_rcpf(ao * ac);
  return sc * rd2;
}

template <int LAYER, bool XPF32>
__global__ __launch_bounds__(512) void lstm_scan(const void* xp, const unsigned short* swh,
                                                 unsigned short* out0, float* dout) {
  using gxT = typename std::conditional<XPF32, float2, unsigned int>::type;
  int dir = blockIdx.x >> 2;
  int q = blockIdx.x & 3;
  int wid = threadIdx.x >> 6, lane = threadIdx.x & 63;
  int c15 = lane & 15;
  int rm = lane & 7;
  bool lov = lane < 32;
  int col = wid * 16 + c15;
  int rowbase = ((lane >> 4) & 1) * 4 + ((lane >> 5) & 1) * 2;  // {0,4,2,6}

  __shared__ __align__(16) unsigned short hA[1024];  // 8 rows x 128 cols bf16
  __shared__ __align__(16) unsigned short hB[1024];

  // Wh fragments (pre-scaled, pre-fragged): 16 contiguous b128 loads
  const unsigned short* whbase = swh + (size_t)LAYER * 131072 + (size_t)dir * 65536;
  short8 whf[4][4];
#pragma unroll
  for (int g = 0; g < 4; ++g)
#pragma unroll
    for (int ks = 0; ks < 4; ++ks)
      whf[g][ks] = *(const short8*)(whbase + g * 16384 + ks * 4096 + wid * 512 + lane * 8);

  if (threadIdx.x < 512) {
    ((unsigned int*)hA)[threadIdx.x & 511] = 0u;
    ((unsigned int*)hB)[threadIdx.x & 511] = 0u;
  }

  // LDS read offsets (A-frags of h), rows duplicated via &7, XOR-swizzled
  int aoff[4];
#pragma unroll
  for (int ks = 0; ks < 4; ++ks) {
    int kb = ks * 64 + ((lane >> 4) << 4);
    aoff[ks] = rm * 256 + (kb ^ (rm << 4));
  }
  // LDS write offsets for this thread's 2 rows
  int woff0 = rowbase * 256 + ((col * 2) ^ (rowbase << 4));
  int woff1 = (rowbase + 1) * 256 + ((col * 2) ^ ((rowbase + 1) << 4));

  // gx addressing (compact layout)
  const gxT* xpg = (const gxT*)xp + (size_t)dir * 16777216u;
  int og0 = ((q * 4 + 0) * 8 + wid) * 64 + lane;
  int og1 = ((q * 4 + 1) * 8 + wid) * 64 + lane;
  int og2 = ((q * 4 + 2) * 8 + wid) * 64 + lane;
  int og3 = ((q * 4 + 3) * 8 + wid) * 64 + lane;

  int grow = q * 8 + rowbase;                          // global batch row (first of 2)
  int obout0 = grow * 256 + dir * 128 + col;           // within out0 t-block
  int obout1 = obout0 + 256;
  size_t dlo0 = ((size_t)grow * T * 256 + dir * 128 + col) * 4;   // dout byte offsets
  size_t dlo1 = dlo0 + (size_t)T * 256 * 4;

  float cs0 = 0.f, cs1 = 0.f;

  int t0 = dir ? (T - 1) : 0;
  int ts = dir ? -1 : 1;

  const gxT* gxp = xpg + (size_t)t0 * 8192;
  unsigned short* outp = out0 + (size_t)t0 * 8192;
  char* dp = (char*)dout + (size_t)t0 * 1024;
  const ptrdiff_t GXS = (ptrdiff_t)ts * 8192;
  const ptrdiff_t OUS = (ptrdiff_t)ts * 8192;
  const ptrdiff_t DPS = (ptrdiff_t)ts * 1024;

  gxT ga0 = gxp[og0], ga1 = gxp[og1], ga2 = gxp[og2], ga3 = gxp[og3];
  gxT gb0, gb1, gb2, gb3;
  __syncthreads();

#define STEP(RD, WR, GC0, GC1, GC2, GC3, GN0, GN1, GN2, GN3)                       \
  {                                                                                \
    short8 af0 = *(const short8*)((const char*)(RD) + aoff[0]);                    \
    short8 af1 = *(const short8*)((const char*)(RD) + aoff[1]);                    \
    short8 af2 = *(const short8*)((const char*)(RD) + aoff[2]);                    \
    short8 af3 = *(const short8*)((const char*)(RD) + aoff[3]);                    \
    const f32x4 zz = {0.f, 0.f, 0.f, 0.f};                                         \
    f32x4 acc0 = __builtin_amdgcn_mfma_f32_16x16x32_bf16(af0, whf[0][0], zz, 0, 0, 0); \
    f32x4 acc1 = __builtin_amdgcn_mfma_f32_16x16x32_bf16(af0, whf[1][0], zz, 0, 0, 0); \
    f32x4 acc2 = __builtin_amdgcn_mfma_f32_16x16x32_bf16(af0, whf[2][0], zz, 0, 0, 0); \
    f32x4 acc3 = __builtin_amdgcn_mfma_f32_16x16x32_bf16(af0, whf[3][0], zz, 0, 0, 0); \
    gxp += GXS;                                                                    \
    GN0 = gxp[og0]; GN1 = gxp[og1]; GN2 = gxp[og2]; GN3 = gxp[og3];                \
    acc0 = __builtin_amdgcn_mfma_f32_16x16x32_bf16(af1, whf[0][1], acc0, 0, 0, 0); \
    acc1 = __builtin_amdgcn_mfma_f32_16x16x32_bf16(af1, whf[1][1], acc1, 0, 0, 0); \
    acc2 = __builtin_amdgcn_mfma_f32_16x16x32_bf16(af1, whf[2][1], acc2, 0, 0, 0); \
    acc3 = __builtin_amdgcn_mfma_f32_16x16x32_bf16(af1, whf[3][1], acc3, 0, 0, 0); \
    acc0 = __builtin_amdgcn_mfma_f32_16x16x32_bf16(af2, whf[0][2], acc0, 0, 0, 0); \
    acc1 = __builtin_amdgcn_mfma_f32_16x16x32_bf16(af2, whf[1][2], acc1, 0, 0, 0); \
    acc2 = __builtin_amdgcn_mfma_f32_16x16x32_bf16(af2, whf[2][2], acc2, 0, 0, 0); \
    acc3 = __builtin_amdgcn_mfma_f32_16x16x32_bf16(af2, whf[3][2], acc3, 0, 0, 0); \
    acc0 = __builtin_amdgcn_mfma_f32_16x16x32_bf16(af3, whf[0][3], acc0, 0, 0, 0); \
    acc1 = __builtin_amdgcn_mfma_f32_16x16x32_bf16(af3, whf[1][3], acc1, 0, 0, 0); \
    acc2 = __builtin_amdgcn_mfma_f32_16x16x32_bf16(af3, whf[2][3], acc2, 0, 0, 0); \
    acc3 = __builtin_amdgcn_mfma_f32_16x16x32_bf16(af3, whf[3][3], acc3, 0, 0, 0); \
    float2 gi = gxpair(GC0), gf = gxpair(GC1), gg2 = gxpair(GC2), go = gxpair(GC3); \
    float pi0 = (lov ? acc0[0] : acc0[2]) + gi.x;                                  \
    float pi1 = (lov ? acc0[1] : acc0[3]) + gi.y;                                  \
    float pf0 = (lov ? acc1[0] : acc1[2]) + gf.x;                                  \
    float pf1 = (lov ? acc1[1] : acc1[3]) + gf.y;                                  \
    float pg0 = (lov ? acc2[0] : acc2[2]) + gg2.x;                                 \
    float pg1 = (lov ? acc2[1] : acc2[3]) + gg2.y;                                 \
    float po0 = (lov ? acc3[0] : acc3[2]) + go.x;                                  \
    float po1 = (lov ? acc3[1] : acc3[3]) + go.y;                                  \
    float h0v = actstep(pi0, pf0, pg0, po0, cs0);                                  \
    float h1v = actstep(pi1, pf1, pg1, po1, cs1);                                  \
    unsigned int pk;                                                               \
    asm("v_cvt_pk_bf16_f32 %0, %1, %2" : "=v"(pk) : "v"(h0v), "v"(h1v));           \
    unsigned short hb0 = (unsigned short)pk, hb1 = (unsigned short)(pk >> 16);     \
    *(unsigned short*)((char*)(WR) + woff0) = hb0;                                 \
    *(unsigned short*)((char*)(WR) + woff1) = hb1;                                 \
    if (LAYER == 0) {                                                              \
      outp[obout0] = hb0;                                                          \
      outp[obout1] = hb1;                                                          \
      outp += OUS;                                                                 \
    } else {                                                                       \
      *(float*)(dp + dlo0) = h0v;                                                  \
      *(float*)(dp + dlo1) = h1v;                                                  \
      dp += DPS;                                                                   \
    }                                                                              \
    asm volatile("s_waitcnt lgkmcnt(0)" ::: "memory");                             \
    __builtin_amdgcn_s_barrier();                                                  \
    asm volatile("" ::: "memory");                                                 \
  }

  for (int s = 0; s < T; s += 2) {
    STEP(hA, hB, ga0, ga1, ga2, ga3, gb0, gb1, gb2, gb3);
    STEP(hB, hA, gb0, gb1, gb2, gb3, ga0, ga1, ga2, ga3);
  }
#undef STEP

  if constexpr (LAYER == 1) {
    dout[XOUT + (size_t)grow * 256 + dir * 128 + col] = cs0;
    dout[XOUT + (size_t)(grow + 1) * 256 + dir * 128 + col] = cs1;
  }
}

// ---------------------------------------------------------------------------
extern "C" void kernel_launch(void* const* d_in, const int* in_sizes, int n_in,
                              void* d_out, int out_size, void* d_ws, size_t ws_size,
                              hipStream_t stream) {
  const float* x    = (const float*)d_in[0];
  const float* wxf0 = (const float*)d_in[1];
  const float* whf0 = (const float*)d_in[2];
  const float* wxb0 = (const float*)d_in[3];
  const float* whb0 = (const float*)d_in[4];
  const float* wxf1 = (const float*)d_in[5];
  const float* whf1 = (const float*)d_in[6];
  const float* wxb1 = (const float*)d_in[7];
  const float* whb1 = (const float*)d_in[8];
  const float* bf0  = (const float*)d_in[9];
  const float* bb0  = (const float*)d_in[10];
  const float* bf1  = (const float*)d_in[11];
  const float* bb1  = (const float*)d_in[12];
  float* dout = (float*)d_out;

  // ws: [xp][out0 bf16][sw0][sw1][swh]
  const size_t needF32 = 268435456u + 33554432u + 262144u + 524288u + 524288u;
  bool xpf32 = ws_size >= needF32;
  size_t xpBytes = xpf32 ? 268435456u : 134217728u;
  unsigned char* ws = (unsigned char*)d_ws;
  void* xp = (void*)ws;
  unsigned short* out0 = (unsigned short*)(ws + xpBytes);
  unsigned short* sw0  = (unsigned short*)(ws + xpBytes + 33554432u);
  unsigned short* sw1  = sw0 + 2 * 65536;
  unsigned short* swh  = sw1 + 2 * 131072;

  prep_wx<<<1536, 256, 0, stream>>>(wxf0, wxb0, wxf1, wxb1, sw0, sw1);
  prep_wh<<<1024, 256, 0, stream>>>(whf0, whb0, whf1, whb1, swh);

  if (xpf32) {
    input_proj<0, true><<<dim3(2048, 2), 256, 0, stream>>>(x, nullptr, sw0, bf0, bb0, xp);
    lstm_scan<0, true><<<8, 512, 0, stream>>>(xp, swh, out0, dout);
    input_proj<1, true><<<dim3(2048, 2), 256, 0, stream>>>(nullptr, out0, sw1, bf1, bb1, xp);
    lstm_scan<1, true><<<8, 512, 0, stream>>>(xp, swh, out0, dout);
  } else {
    input_proj<0, false><<<dim3(2048, 2), 256, 0, stream>>>(x, nullptr, sw0, bf0, bb0, xp);
    lstm_scan<0, false><<<8, 512, 0, stream>>>(xp, swh, out0, dout);
    input_proj<1, false><<<dim3(2048, 2), 256, 0, stream>>>(nullptr, out0, sw1, bf1, bb1, xp);
    lstm_scan<1, false><<<8, 512, 0, stream>>>(xp, swh, out0, dout);
  }
}

// Round 6
// 1976.016 us; speedup vs baseline: 4.0696x; 1.2121x over previous
//
#include <hip/hip_runtime.h>
#include <hip/hip_bf16.h>
#include <stdint.h>
#include <type_traits>

// Bidirectional 2-layer LSTM, B=32, T=2048, F=H=128, G=4H=512.
// prep (Wx,Wh -> scaled bf16 frags) -> proj L0 -> scan L0 (16 WGs: dir x 8
// batch-octants of 4 rows) -> proj L1 -> scan L1. Gate pre-activations are
// pre-scaled by -log2e (i,f,o) / -2log2e (g) so sigmoid = rcp(1+exp2(y)).
// 7-trans common-denominator activation; 1 state elem per lane (rows
// duplicated 4x in the M-tile, reg selected by 3 cndmask).

#define DEVINL __device__ __forceinline__

typedef __attribute__((ext_vector_type(8))) short short8;
typedef __attribute__((ext_vector_type(4))) float f32x4;

static constexpr int T = 2048;
static constexpr size_t XOUT = (size_t)32 * T * 256;
static constexpr float L2E = 1.4426950408889634f;
static constexpr float M2L2E = -2.8853900817779268f;

DEVINL unsigned short f2bf(float f) {
  unsigned int u = __float_as_uint(f);
  u += 0x7FFFu + ((u >> 16) & 1u);  // RNE
  return (unsigned short)(u >> 16);
}
DEVINL float gate_scale(int g) { return (g == 2) ? M2L2E : -L2E; }

// ---------------------------------------------------------------------------
// prep_wx: Wx (f32 [K][512]) -> scaled bf16 B-frags [dir][ng(32)][ks][lane][e8]
// ---------------------------------------------------------------------------
__global__ __launch_bounds__(256) void prep_wx(const float* wxf0, const float* wxb0,
                                               const float* wxf1, const float* wxb1,
                                               unsigned short* sw0, unsigned short* sw1) {
  int idx = blockIdx.x * 256 + threadIdx.x;
  if (idx < 2 * 65536) {                       // layer 0, KS=4
    int d = idx >> 16;
    int local = idx & 65535;
    const float* w = d ? wxb0 : wxf0;
    int e = local & 7, lane = (local >> 3) & 63, ks = (local >> 9) & 3, ng = local >> 11;
    int col = ng * 16 + (lane & 15);
    int k = ks * 32 + ((lane >> 4) << 3) + e;
    sw0[idx] = f2bf(w[k * 512 + col] * gate_scale(ng >> 3));
  } else {                                     // layer 1, KS=8
    int j = idx - 2 * 65536;
    if (j < 2 * 131072) {
      int d = j >> 17;
      int local = j & 131071;
      const float* w = d ? wxb1 : wxf1;
      int e = local & 7, lane = (local >> 3) & 63, ks = (local >> 9) & 7, ng = local >> 12;
      int col = ng * 16 + (lane & 15);
      int k = ks * 32 + ((lane >> 4) << 3) + e;
      sw1[j] = f2bf(w[k * 512 + col] * gate_scale(ng >> 3));
    }
  }
}

// ---------------------------------------------------------------------------
// prep_wh: Wh (f32 [128][512]) -> scaled bf16 frags, contiguous per wave:
// idx bits: e(0-2) lane(3-8) wid(9-11) ks(12-13) g(14-15) dir(16) layer(17)
// ---------------------------------------------------------------------------
__global__ __launch_bounds__(256) void prep_wh(const float* whf0, const float* whb0,
                                               const float* whf1, const float* whb1,
                                               unsigned short* swh) {
  int idx = blockIdx.x * 256 + threadIdx.x;
  if (idx >= 262144) return;
  int e = idx & 7, lane = (idx >> 3) & 63, wid = (idx >> 9) & 7;
  int ks = (idx >> 12) & 3, g = (idx >> 14) & 3, dir = (idx >> 16) & 1, layer = (idx >> 17) & 1;
  const float* w = layer ? (dir ? whb1 : whf1) : (dir ? whb0 : whf0);
  int col = g * 128 + wid * 16 + (lane & 15);
  int k = ks * 32 + ((lane >> 4) << 3) + e;
  swh[idx] = f2bf(w[k * 512 + col] * gate_scale(g));
}

// ---------------------------------------------------------------------------
// input_proj: xp[dir][t][q(8)][row(4)][col(128)][g(4)] = A(t)@Wx_scaled + b.
// Scan thread (q, row=p, col) then loads ONE float4 (4 gates).
// Per-t-per-dir block = 16384 f32 (64KB f32 / 32KB bf16).
// ---------------------------------------------------------------------------
template <int LAYER, bool XPF32>
__global__ __launch_bounds__(256) void input_proj(const float* x, const unsigned short* a_bf,
                                                  const unsigned short* wsw,
                                                  const float* bias_f, const float* bias_b,
                                                  void* xp_out) {
  constexpr int KS = (LAYER == 0) ? 4 : 8;
  int t = blockIdx.x, dir = blockIdx.y;
  int wid = threadIdx.x >> 6, lane = threadIdx.x & 63;   // wid = 0..3
  int p = lane >> 4, c15 = lane & 15;
  const unsigned short* wbase = wsw + (size_t)dir * (32 * KS * 64 * 8);
  const float* bias = dir ? bias_b : bias_f;

  short8 afrag[2][KS];
#pragma unroll
  for (int mt = 0; mt < 2; ++mt) {
#pragma unroll
    for (int ks = 0; ks < KS; ++ks) {
      int m = c15 + mt * 16;
      int kk = ks * 32 + (p << 3);
      if constexpr (LAYER == 0) {
        const float* ap = x + (size_t)m * (T * 128) + (size_t)t * 128 + kk;
        float4 lov = *(const float4*)ap;
        float4 hiv = *(const float4*)(ap + 4);
        short8 s;
        s[0] = (short)f2bf(lov.x); s[1] = (short)f2bf(lov.y);
        s[2] = (short)f2bf(lov.z); s[3] = (short)f2bf(lov.w);
        s[4] = (short)f2bf(hiv.x); s[5] = (short)f2bf(hiv.y);
        s[6] = (short)f2bf(hiv.z); s[7] = (short)f2bf(hiv.w);
        afrag[mt][ks] = s;
      } else {
        afrag[mt][ks] = *(const short8*)(a_bf + ((size_t)t * 32 + m) * 256 + kk);
      }
    }
  }

#pragma unroll
  for (int ngi = 0; ngi < 8; ++ngi) {
    int ng = wid * 8 + ngi;                    // g = wid, wd = ngi
    int g = ng >> 3, wd = ng & 7;
    f32x4 acc0 = {0.f, 0.f, 0.f, 0.f};
    f32x4 acc1 = {0.f, 0.f, 0.f, 0.f};
#pragma unroll
    for (int ks = 0; ks < KS; ++ks) {
      short8 b = *(const short8*)(wbase + ((size_t)(ng * KS + ks) * 64 + lane) * 8);
      acc0 = __builtin_amdgcn_mfma_f32_16x16x32_bf16(afrag[0][ks], b, acc0, 0, 0, 0);
      acc1 = __builtin_amdgcn_mfma_f32_16x16x32_bf16(afrag[1][ks], b, acc1, 0, 0, 0);
    }
    float bs = bias[ng * 16 + c15] * gate_scale(g);
    int gcol = wd * 16 + c15;
#pragma unroll
    for (int mt = 0; mt < 2; ++mt) {
      f32x4 v = (mt == 0) ? acc0 : acc1;
      v[0] += bs; v[1] += bs; v[2] += bs; v[3] += bs;
      // batch row = mt*16 + p*4 + r  ->  q = mt*4+p, rowInQ = r
      size_t base = (size_t)t * 16384 + (size_t)((mt * 4 + p) * 2048 + gcol * 4 + g);
      if constexpr (XPF32) {
        float* xpf = (float*)xp_out + (size_t)dir * ((size_t)T * 16384);
#pragma unroll
        for (int r = 0; r < 4; ++r) xpf[base + r * 512] = v[r];
      } else {
        unsigned short* xpb = (unsigned short*)xp_out + (size_t)dir * ((size_t)T * 16384);
#pragma unroll
        for (int r = 0; r < 4; ++r) xpb[base + r * 512] = f2bf(v[r]);
      }
    }
  }
}

// ---------------------------------------------------------------------------
// lstm_scan: 16 persistent WGs (blockIdx = dir*8 + octant q), 8 waves each.
// Wave wid owns 16 h-cols (all 4 gates) for 4 batch rows (duplicated 4x in
// the M-tile). Each lane handles exactly 1 state elem (row p = lane>>4).
// Wh in regs; h double-buffered in LDS (4 x 288B rows, conflict-free);
// gx = one float4/thread, prefetched 1 step ahead. 1 lgkm barrier/step.
// ---------------------------------------------------------------------------
DEVINL f32x4 gx2v(float4 v) { f32x4 r; r[0]=v.x; r[1]=v.y; r[2]=v.z; r[3]=v.w; return r; }
DEVINL f32x4 gx2v(uint2 u) {
  f32x4 r;
  r[0] = __uint_as_float(u.x << 16);
  r[1] = __uint_as_float(u.x & 0xFFFF0000u);
  r[2] = __uint_as_float(u.y << 16);
  r[3] = __uint_as_float(u.y & 0xFFFF0000u);
  return r;
}
DEVINL float sel4(f32x4 a, int p) {
  float s01 = (p & 1) ? a[1] : a[0];
  float s23 = (p & 1) ? a[3] : a[2];
  return (p & 2) ? s23 : s01;
}
DEVINL float actstep(float pi, float pf, float pg, float po, float& c) {
  float ei = __builtin_amdgcn_exp2f(pi);
  float ef = __builtin_amdgcn_exp2f(pf);
  float eg = __builtin_amdgcn_exp2f(pg);
  float eo = __builtin_amdgcn_exp2f(po);
  float ai = 1.0f + ei, av = 1.0f + ef, ag = 1.0f + eg, sg = 1.0f - eg;
  float pp = ai * ag;
  float num = __builtin_fmaf(c, pp, sg * av);
  float rd = __builtin_amdgcn_rcpf(av * pp);
  float cn = num * rd;
  c = cn;
  float ec = __builtin_amdgcn_exp2f(M2L2E * cn);
  float ao = 1.0f + eo, ac = 1.0f + ec, sc = 1.0f - ec;
  float rd2 = __builtin_amdgcn_rcpf(ao * ac);
  return sc * rd2;
}

template <int LAYER, bool XPF32>
__global__ __launch_bounds__(512) void lstm_scan(const void* xp, const unsigned short* swh,
                                                 unsigned short* out0, float* dout) {
  using gxT = typename std::conditional<XPF32, float4, uint2>::type;
  int dir = blockIdx.x >> 3;
  int q = blockIdx.x & 7;
  int wid = threadIdx.x >> 6, lane = threadIdx.x & 63;
  int c15 = lane & 15, p = lane >> 4;
  int col = wid * 16 + c15;

  __shared__ __align__(16) unsigned char hA[1280];  // 4 rows x 288B (128 bf16 + pad)
  __shared__ __align__(16) unsigned char hB[1280];

  // Wh fragments (pre-scaled, pre-fragged): 16 contiguous b128 loads
  const unsigned short* whbase = swh + (size_t)LAYER * 131072 + (size_t)dir * 65536;
  short8 whf[4][4];
#pragma unroll
  for (int g = 0; g < 4; ++g)
#pragma unroll
    for (int ks = 0; ks < 4; ++ks)
      whf[g][ks] = *(const short8*)(whbase + g * 16384 + ks * 4096 + wid * 512 + lane * 8);

  if (threadIdx.x < 288) {
    ((unsigned int*)hA)[threadIdx.x] = 0u;
    ((unsigned int*)hB)[threadIdx.x] = 0u;
  }

  // A-frag read offsets: row = lane&3 (4x duplicated), k-slot = lane>>4
  int aoff[4];
#pragma unroll
  for (int ks = 0; ks < 4; ++ks)
    aoff[ks] = (lane & 3) * 288 + ((lane >> 4) << 4) + ks * 64;
  // h write offset: row p, col
  int woff = p * 288 + col * 2;

  // gx: one gxT per thread per step
  const gxT* xpg = (const gxT*)xp + (size_t)dir * ((size_t)T * 4096);
  int og = q * 512 + p * 128 + col;

  int b = q * 4 + p;                                   // global batch row
  float cs = 0.f;

  int t0 = dir ? (T - 1) : 0;
  int ts = dir ? -1 : 1;

  const gxT* gxp = xpg + (size_t)t0 * 4096;
  unsigned short* outp = out0 + (size_t)t0 * 8192 + b * 256 + dir * 128 + col;
  float* dp = dout + ((size_t)b * T + t0) * 256 + dir * 128 + col;
  const ptrdiff_t GXS = (ptrdiff_t)ts * 4096;
  const ptrdiff_t OUS = (ptrdiff_t)ts * 8192;
  const ptrdiff_t DPS = (ptrdiff_t)ts * 256;

  gxT ga = gxp[og];
  gxT gb;
  __syncthreads();

#define STEP(RD, WR, GC, GN)                                                       \
  {                                                                                \
    short8 af0 = *(const short8*)((const char*)(RD) + aoff[0]);                    \
    short8 af1 = *(const short8*)((const char*)(RD) + aoff[1]);                    \
    short8 af2 = *(const short8*)((const char*)(RD) + aoff[2]);                    \
    short8 af3 = *(const short8*)((const char*)(RD) + aoff[3]);                    \
    const f32x4 zz = {0.f, 0.f, 0.f, 0.f};                                         \
    f32x4 acc0 = __builtin_amdgcn_mfma_f32_16x16x32_bf16(af0, whf[0][0], zz, 0, 0, 0); \
    f32x4 acc1 = __builtin_amdgcn_mfma_f32_16x16x32_bf16(af0, whf[1][0], zz, 0, 0, 0); \
    f32x4 acc2 = __builtin_amdgcn_mfma_f32_16x16x32_bf16(af0, whf[2][0], zz, 0, 0, 0); \
    f32x4 acc3 = __builtin_amdgcn_mfma_f32_16x16x32_bf16(af0, whf[3][0], zz, 0, 0, 0); \
    gxp += GXS;                                                                    \
    GN = gxp[og];                                                                  \
    acc0 = __builtin_amdgcn_mfma_f32_16x16x32_bf16(af1, whf[0][1], acc0, 0, 0, 0); \
    acc1 = __builtin_amdgcn_mfma_f32_16x16x32_bf16(af1, whf[1][1], acc1, 0, 0, 0); \
    acc2 = __builtin_amdgcn_mfma_f32_16x16x32_bf16(af1, whf[2][1], acc2, 0, 0, 0); \
    acc3 = __builtin_amdgcn_mfma_f32_16x16x32_bf16(af1, whf[3][1], acc3, 0, 0, 0); \
    acc0 = __builtin_amdgcn_mfma_f32_16x16x32_bf16(af2, whf[0][2], acc0, 0, 0, 0); \
    acc1 = __builtin_amdgcn_mfma_f32_16x16x32_bf16(af2, whf[1][2], acc1, 0, 0, 0); \
    acc2 = __builtin_amdgcn_mfma_f32_16x16x32_bf16(af2, whf[2][2], acc2, 0, 0, 0); \
    acc3 = __builtin_amdgcn_mfma_f32_16x16x32_bf16(af2, whf[3][2], acc3, 0, 0, 0); \
    acc0 = __builtin_amdgcn_mfma_f32_16x16x32_bf16(af3, whf[0][3], acc0, 0, 0, 0); \
    acc1 = __builtin_amdgcn_mfma_f32_16x16x32_bf16(af3, whf[1][3], acc1, 0, 0, 0); \
    acc2 = __builtin_amdgcn_mfma_f32_16x16x32_bf16(af3, whf[2][3], acc2, 0, 0, 0); \
    acc3 = __builtin_amdgcn_mfma_f32_16x16x32_bf16(af3, whf[3][3], acc3, 0, 0, 0); \
    f32x4 gv = gx2v(GC);                                                           \
    float pi = sel4(acc0, p) + gv[0];                                              \
    float pf = sel4(acc1, p) + gv[1];                                              \
    float pg = sel4(acc2, p) + gv[2];                                              \
    float po = sel4(acc3, p) + gv[3];                                              \
    float hv = actstep(pi, pf, pg, po, cs);                                        \
    unsigned int pk;                                                               \
    asm("v_cvt_pk_bf16_f32 %0, %1, %2" : "=v"(pk) : "v"(hv), "v"(hv));             \
    unsigned short hb = (unsigned short)pk;                                        \
    *(unsigned short*)((char*)(WR) + woff) = hb;                                   \
    if (LAYER == 0) {                                                              \
      *outp = hb;                                                                  \
      outp += OUS;                                                                 \
    } else {                                                                       \
      *dp = hv;                                                                    \
      dp += DPS;                                                                   \
    }                                                                              \
    asm volatile("s_waitcnt lgkmcnt(0)" ::: "memory");                             \
    __builtin_amdgcn_s_barrier();                                                  \
    asm volatile("" ::: "memory");                                                 \
  }

  for (int s = 0; s < T; s += 2) {
    STEP(hA, hB, ga, gb);
    STEP(hB, hA, gb, ga);
  }
#undef STEP

  if constexpr (LAYER == 1) {
    dout[XOUT + (size_t)b * 256 + dir * 128 + col] = cs;
  }
}

// ---------------------------------------------------------------------------
extern "C" void kernel_launch(void* const* d_in, const int* in_sizes, int n_in,
                              void* d_out, int out_size, void* d_ws, size_t ws_size,
                              hipStream_t stream) {
  const float* x    = (const float*)d_in[0];
  const float* wxf0 = (const float*)d_in[1];
  const float* whf0 = (const float*)d_in[2];
  const float* wxb0 = (const float*)d_in[3];
  const float* whb0 = (const float*)d_in[4];
  const float* wxf1 = (const float*)d_in[5];
  const float* whf1 = (const float*)d_in[6];
  const float* wxb1 = (const float*)d_in[7];
  const float* whb1 = (const float*)d_in[8];
  const float* bf0  = (const float*)d_in[9];
  const float* bb0  = (const float*)d_in[10];
  const float* bf1  = (const float*)d_in[11];
  const float* bb1  = (const float*)d_in[12];
  float* dout = (float*)d_out;

  // ws: [xp][out0 bf16][sw0][sw1][swh]
  const size_t needF32 = 268435456u + 33554432u + 262144u + 524288u + 524288u;
  bool xpf32 = ws_size >= needF32;
  size_t xpBytes = xpf32 ? 268435456u : 134217728u;
  unsigned char* ws = (unsigned char*)d_ws;
  void* xp = (void*)ws;
  unsigned short* out0 = (unsigned short*)(ws + xpBytes);
  unsigned short* sw0  = (unsigned short*)(ws + xpBytes + 33554432u);
  unsigned short* sw1  = sw0 + 2 * 65536;
  unsigned short* swh  = sw1 + 2 * 131072;

  prep_wx<<<1536, 256, 0, stream>>>(wxf0, wxb0, wxf1, wxb1, sw0, sw1);
  prep_wh<<<1024, 256, 0, stream>>>(whf0, whb0, whf1, whb1, swh);

  if (xpf32) {
    input_proj<0, true><<<dim3(2048, 2), 256, 0, stream>>>(x, nullptr, sw0, bf0, bb0, xp);
    lstm_scan<0, true><<<16, 512, 0, stream>>>(xp, swh, out0, dout);
    input_proj<1, true><<<dim3(2048, 2), 256, 0, stream>>>(nullptr, out0, sw1, bf1, bb1, xp);
    lstm_scan<1, true><<<16, 512, 0, stream>>>(xp, swh, out0, dout);
  } else {
    input_proj<0, false><<<dim3(2048, 2), 256, 0, stream>>>(x, nullptr, sw0, bf0, bb0, xp);
    lstm_scan<0, false><<<16, 512, 0, stream>>>(xp, swh, out0, dout);
    input_proj<1, false><<<dim3(2048, 2), 256, 0, stream>>>(nullptr, out0, sw1, bf1, bb1, xp);
    lstm_scan<1, false><<<16, 512, 0, stream>>>(xp, swh, out0, dout);
  }
}

// Round 7
// 1778.302 us; speedup vs baseline: 4.5221x; 1.1112x over previous
//
#include <hip/hip_runtime.h>
#include <hip/hip_bf16.h>
#include <stdint.h>
#include <type_traits>

// Bidirectional 2-layer LSTM, B=32, T=2048, F=H=128, G=4H=512.
// prep (Wx,Wh -> scaled bf16 frags) -> proj L0 -> scan L0 (16 WGs: dir x 8
// batch-octants of 4 rows) -> proj L1 -> scan L1. Gate pre-activations are
// pre-scaled by -log2e (i,f,o) / -2log2e (g) so sigmoid = rcp(1+exp2(y)).
// 7-trans common-denominator activation; 1 state elem per lane. Rows are
// duplicated CONSECUTIVELY (A row m = real row m>>2) so every acc reg of
// lane-group p equals real row p -> no select tree. Gate-major MFMA order
// lets each gate's exp2 issue under the remaining MFMAs.

#define DEVINL __device__ __forceinline__

typedef __attribute__((ext_vector_type(8))) short short8;
typedef __attribute__((ext_vector_type(4))) float f32x4;

static constexpr int T = 2048;
static constexpr size_t XOUT = (size_t)32 * T * 256;
static constexpr float L2E = 1.4426950408889634f;
static constexpr float M2L2E = -2.8853900817779268f;

DEVINL unsigned short f2bf(float f) {
  unsigned int u = __float_as_uint(f);
  u += 0x7FFFu + ((u >> 16) & 1u);  // RNE
  return (unsigned short)(u >> 16);
}
DEVINL float gate_scale(int g) { return (g == 2) ? M2L2E : -L2E; }

// ---------------------------------------------------------------------------
// prep_wx: Wx (f32 [K][512]) -> scaled bf16 B-frags [dir][ng(32)][ks][lane][e8]
// ---------------------------------------------------------------------------
__global__ __launch_bounds__(256) void prep_wx(const float* wxf0, const float* wxb0,
                                               const float* wxf1, const float* wxb1,
                                               unsigned short* sw0, unsigned short* sw1) {
  int idx = blockIdx.x * 256 + threadIdx.x;
  if (idx < 2 * 65536) {                       // layer 0, KS=4
    int d = idx >> 16;
    int local = idx & 65535;
    const float* w = d ? wxb0 : wxf0;
    int e = local & 7, lane = (local >> 3) & 63, ks = (local >> 9) & 3, ng = local >> 11;
    int col = ng * 16 + (lane & 15);
    int k = ks * 32 + ((lane >> 4) << 3) + e;
    sw0[idx] = f2bf(w[k * 512 + col] * gate_scale(ng >> 3));
  } else {                                     // layer 1, KS=8
    int j = idx - 2 * 65536;
    if (j < 2 * 131072) {
      int d = j >> 17;
      int local = j & 131071;
      const float* w = d ? wxb1 : wxf1;
      int e = local & 7, lane = (local >> 3) & 63, ks = (local >> 9) & 7, ng = local >> 12;
      int col = ng * 16 + (lane & 15);
      int k = ks * 32 + ((lane >> 4) << 3) + e;
      sw1[j] = f2bf(w[k * 512 + col] * gate_scale(ng >> 3));
    }
  }
}

// ---------------------------------------------------------------------------
// prep_wh: Wh (f32 [128][512]) -> scaled bf16 frags, contiguous per wave:
// idx bits: e(0-2) lane(3-8) wid(9-11) ks(12-13) g(14-15) dir(16) layer(17)
// ---------------------------------------------------------------------------
__global__ __launch_bounds__(256) void prep_wh(const float* whf0, const float* whb0,
                                               const float* whf1, const float* whb1,
                                               unsigned short* swh) {
  int idx = blockIdx.x * 256 + threadIdx.x;
  if (idx >= 262144) return;
  int e = idx & 7, lane = (idx >> 3) & 63, wid = (idx >> 9) & 7;
  int ks = (idx >> 12) & 3, g = (idx >> 14) & 3, dir = (idx >> 16) & 1, layer = (idx >> 17) & 1;
  const float* w = layer ? (dir ? whb1 : whf1) : (dir ? whb0 : whf0);
  int col = g * 128 + wid * 16 + (lane & 15);
  int k = ks * 32 + ((lane >> 4) << 3) + e;
  swh[idx] = f2bf(w[k * 512 + col] * gate_scale(g));
}

// ---------------------------------------------------------------------------
// input_proj: xp[dir][t][q(8)][row(4)][col(128)][g(4)] = A(t)@Wx_scaled + b.
// Scan thread (q, row=p, col) then loads ONE float4/uint2 (4 gates).
// ---------------------------------------------------------------------------
template <int LAYER, bool XPF32>
__global__ __launch_bounds__(256) void input_proj(const float* x, const unsigned short* a_bf,
                                                  const unsigned short* wsw,
                                                  const float* bias_f, const float* bias_b,
                                                  void* xp_out) {
  constexpr int KS = (LAYER == 0) ? 4 : 8;
  int t = blockIdx.x, dir = blockIdx.y;
  int wid = threadIdx.x >> 6, lane = threadIdx.x & 63;   // wid = 0..3
  int p = lane >> 4, c15 = lane & 15;
  const unsigned short* wbase = wsw + (size_t)dir * (32 * KS * 64 * 8);
  const float* bias = dir ? bias_b : bias_f;

  short8 afrag[2][KS];
#pragma unroll
  for (int mt = 0; mt < 2; ++mt) {
#pragma unroll
    for (int ks = 0; ks < KS; ++ks) {
      int m = c15 + mt * 16;
      int kk = ks * 32 + (p << 3);
      if constexpr (LAYER == 0) {
        const float* ap = x + (size_t)m * (T * 128) + (size_t)t * 128 + kk;
        float4 lov = *(const float4*)ap;
        float4 hiv = *(const float4*)(ap + 4);
        short8 s;
        s[0] = (short)f2bf(lov.x); s[1] = (short)f2bf(lov.y);
        s[2] = (short)f2bf(lov.z); s[3] = (short)f2bf(lov.w);
        s[4] = (short)f2bf(hiv.x); s[5] = (short)f2bf(hiv.y);
        s[6] = (short)f2bf(hiv.z); s[7] = (short)f2bf(hiv.w);
        afrag[mt][ks] = s;
      } else {
        afrag[mt][ks] = *(const short8*)(a_bf + ((size_t)t * 32 + m) * 256 + kk);
      }
    }
  }

#pragma unroll
  for (int ngi = 0; ngi < 8; ++ngi) {
    int ng = wid * 8 + ngi;
    int g = ng >> 3, wd = ng & 7;
    f32x4 acc0 = {0.f, 0.f, 0.f, 0.f};
    f32x4 acc1 = {0.f, 0.f, 0.f, 0.f};
#pragma unroll
    for (int ks = 0; ks < KS; ++ks) {
      short8 b = *(const short8*)(wbase + ((size_t)(ng * KS + ks) * 64 + lane) * 8);
      acc0 = __builtin_amdgcn_mfma_f32_16x16x32_bf16(afrag[0][ks], b, acc0, 0, 0, 0);
      acc1 = __builtin_amdgcn_mfma_f32_16x16x32_bf16(afrag[1][ks], b, acc1, 0, 0, 0);
    }
    float bs = bias[ng * 16 + c15] * gate_scale(g);
    int gcol = wd * 16 + c15;
#pragma unroll
    for (int mt = 0; mt < 2; ++mt) {
      f32x4 v = (mt == 0) ? acc0 : acc1;
      v[0] += bs; v[1] += bs; v[2] += bs; v[3] += bs;
      // batch row = mt*16 + p*4 + r  ->  q = mt*4+p, rowInQ = r
      size_t base = (size_t)t * 16384 + (size_t)((mt * 4 + p) * 2048 + gcol * 4 + g);
      if constexpr (XPF32) {
        float* xpf = (float*)xp_out + (size_t)dir * ((size_t)T * 16384);
#pragma unroll
        for (int r = 0; r < 4; ++r) xpf[base + r * 512] = v[r];
      } else {
        unsigned short* xpb = (unsigned short*)xp_out + (size_t)dir * ((size_t)T * 16384);
#pragma unroll
        for (int r = 0; r < 4; ++r) xpb[base + r * 512] = f2bf(v[r]);
      }
    }
  }
}

// ---------------------------------------------------------------------------
// lstm_scan: 16 persistent WGs (blockIdx = dir*8 + octant q), 8 waves each.
// Wave wid owns 16 h-cols (all 4 gates) for 4 batch rows (consecutive-dup in
// the M-tile: A row m = real row m>>2, so lane-group p's acc[0..3] all equal
// real row p). Wh in regs; h double-buffered in LDS (4 x 288B, conflict-free);
// gx = one float4/uint2 per thread, prefetched 2 steps ahead. 1 barrier/step.
// ---------------------------------------------------------------------------
DEVINL f32x4 gx2v(float4 v) { f32x4 r; r[0]=v.x; r[1]=v.y; r[2]=v.z; r[3]=v.w; return r; }
DEVINL f32x4 gx2v(uint2 u) {
  f32x4 r;
  r[0] = __uint_as_float(u.x << 16);
  r[1] = __uint_as_float(u.x & 0xFFFF0000u);
  r[2] = __uint_as_float(u.y << 16);
  r[3] = __uint_as_float(u.y & 0xFFFF0000u);
  return r;
}

template <int LAYER, bool XPF32>
__global__ __launch_bounds__(512) void lstm_scan(const void* xp, const unsigned short* swh,
                                                 unsigned short* out0, float* dout) {
  using gxT = typename std::conditional<XPF32, float4, uint2>::type;
  int dir = blockIdx.x >> 3;
  int q = blockIdx.x & 7;
  int wid = threadIdx.x >> 6, lane = threadIdx.x & 63;
  int c15 = lane & 15, p = lane >> 4;
  int col = wid * 16 + c15;

  __shared__ __align__(16) unsigned char hA[1280];  // 4 rows x 288B (128 bf16 + pad)
  __shared__ __align__(16) unsigned char hB[1280];

  // Wh fragments (pre-scaled, pre-fragged): 16 contiguous b128 loads
  const unsigned short* whbase = swh + (size_t)LAYER * 131072 + (size_t)dir * 65536;
  short8 whf[4][4];
#pragma unroll
  for (int g = 0; g < 4; ++g)
#pragma unroll
    for (int ks = 0; ks < 4; ++ks)
      whf[g][ks] = *(const short8*)(whbase + g * 16384 + ks * 4096 + wid * 512 + lane * 8);

  if (threadIdx.x < 288) {
    ((unsigned int*)hA)[threadIdx.x] = 0u;
    ((unsigned int*)hB)[threadIdx.x] = 0u;
  }

  // A-frag read offsets: A row m = lane&15 holds real row m>>2 (consecutive dup)
  int aoff[4];
#pragma unroll
  for (int ks = 0; ks < 4; ++ks)
    aoff[ks] = ((lane & 15) >> 2) * 288 + ((lane >> 4) << 4) + ks * 64;
  // h write offset: row p, col
  int woff = p * 288 + col * 2;

  // gx: one gxT per thread per step (uniform base, constant lane index)
  const gxT* gxp = (const gxT*)xp + (size_t)dir * ((size_t)T * 4096);
  int og = q * 512 + p * 128 + col;

  int b = q * 4 + p;                                   // global batch row
  float cs = 0.f;

  int t0 = dir ? (T - 1) : 0;
  int ts = dir ? -1 : 1;

  gxp += (size_t)t0 * 4096;
  // uniform store bases + constant 32-bit lane indices (saddr-form stores)
  unsigned short* outp_u = out0 + (size_t)t0 * 8192;
  float* dp_u = dout + (size_t)t0 * 256;
  unsigned int oidx = (unsigned int)(b * 256 + dir * 128 + col);
  unsigned int didx = (unsigned int)((size_t)b * T * 256 + dir * 128 + col);
  const ptrdiff_t GXS = (ptrdiff_t)ts * 4096;
  const ptrdiff_t OUS = (ptrdiff_t)ts * 8192;
  const ptrdiff_t DPS = (ptrdiff_t)ts * 256;

  gxT ga = gxp[og];
  gxT gb;
  __syncthreads();

#define STEP(RD, WR, GC, GN)                                                       \
  {                                                                                \
    short8 af0 = *(const short8*)((const char*)(RD) + aoff[0]);                    \
    short8 af1 = *(const short8*)((const char*)(RD) + aoff[1]);                    \
    short8 af2 = *(const short8*)((const char*)(RD) + aoff[2]);                    \
    short8 af3 = *(const short8*)((const char*)(RD) + aoff[3]);                    \
    const f32x4 zz = {0.f, 0.f, 0.f, 0.f};                                         \
    f32x4 gv = gx2v(GC);                                                           \
    /* gate 0 (i) */                                                               \
    f32x4 acc0 = __builtin_amdgcn_mfma_f32_16x16x32_bf16(af0, whf[0][0], zz, 0,0,0); \
    acc0 = __builtin_amdgcn_mfma_f32_16x16x32_bf16(af1, whf[0][1], acc0, 0, 0, 0); \
    acc0 = __builtin_amdgcn_mfma_f32_16x16x32_bf16(af2, whf[0][2], acc0, 0, 0, 0); \
    acc0 = __builtin_amdgcn_mfma_f32_16x16x32_bf16(af3, whf[0][3], acc0, 0, 0, 0); \
    float ei = __builtin_amdgcn_exp2f(acc0[0] + gv[0]);                            \
    /* gate 1 (f) */                                                               \
    f32x4 acc1 = __builtin_amdgcn_mfma_f32_16x16x32_bf16(af0, whf[1][0], zz, 0,0,0); \
    acc1 = __builtin_amdgcn_mfma_f32_16x16x32_bf16(af1, whf[1][1], acc1, 0, 0, 0); \
    acc1 = __builtin_amdgcn_mfma_f32_16x16x32_bf16(af2, whf[1][2], acc1, 0, 0, 0); \
    acc1 = __builtin_amdgcn_mfma_f32_16x16x32_bf16(af3, whf[1][3], acc1, 0, 0, 0); \
    float ef = __builtin_amdgcn_exp2f(acc1[0] + gv[1]);                            \
    gxp += GXS;                                                                    \
    GN = gxp[og];                                                                  \
    /* gate 2 (g) */                                                               \
    f32x4 acc2 = __builtin_amdgcn_mfma_f32_16x16x32_bf16(af0, whf[2][0], zz, 0,0,0); \
    acc2 = __builtin_amdgcn_mfma_f32_16x16x32_bf16(af1, whf[2][1], acc2, 0, 0, 0); \
    acc2 = __builtin_amdgcn_mfma_f32_16x16x32_bf16(af2, whf[2][2], acc2, 0, 0, 0); \
    acc2 = __builtin_amdgcn_mfma_f32_16x16x32_bf16(af3, whf[2][3], acc2, 0, 0, 0); \
    float eg = __builtin_amdgcn_exp2f(acc2[0] + gv[2]);                            \
    /* gate 3 (o) */                                                               \
    f32x4 acc3 = __builtin_amdgcn_mfma_f32_16x16x32_bf16(af0, whf[3][0], zz, 0,0,0); \
    acc3 = __builtin_amdgcn_mfma_f32_16x16x32_bf16(af1, whf[3][1], acc3, 0, 0, 0); \
    acc3 = __builtin_amdgcn_mfma_f32_16x16x32_bf16(af2, whf[3][2], acc3, 0, 0, 0); \
    acc3 = __builtin_amdgcn_mfma_f32_16x16x32_bf16(af3, whf[3][3], acc3, 0, 0, 0); \
    float eo = __builtin_amdgcn_exp2f(acc3[0] + gv[3]);                            \
    /* combine: 7-trans common-denominator activation */                           \
    float ai = 1.0f + ei, av = 1.0f + ef, ag = 1.0f + eg, sg = 1.0f - eg;          \
    float pp = ai * ag;                                                            \
    float num = __builtin_fmaf(cs, pp, sg * av);                                   \
    float rd = __builtin_amdgcn_rcpf(av * pp);                                     \
    float cn = num * rd;                                                           \
    cs = cn;                                                                       \
    float ec = __builtin_amdgcn_exp2f(M2L2E * cn);                                 \
    float ao = 1.0f + eo, ac = 1.0f + ec, sc = 1.0f - ec;                          \
    float rd2 = __builtin_amdgcn_rcpf(ao * ac);                                    \
    float hv = sc * rd2;                                                           \
    unsigned int pk;                                                               \
    asm("v_cvt_pk_bf16_f32 %0, %1, %2" : "=v"(pk) : "v"(hv), "v"(hv));             \
    unsigned short hb = (unsigned short)pk;                                        \
    *(unsigned short*)((char*)(WR) + woff) = hb;                                   \
    if (LAYER == 0) {                                                              \
      outp_u[oidx] = hb;                                                           \
      outp_u += OUS;                                                               \
    } else {                                                                       \
      dp_u[didx] = hv;                                                             \
      dp_u += DPS;                                                                 \
    }                                                                              \
    asm volatile("s_waitcnt lgkmcnt(0)" ::: "memory");                             \
    __builtin_amdgcn_s_barrier();                                                  \
    asm volatile("" ::: "memory");                                                 \
  }

  for (int s = 0; s < T; s += 4) {
    STEP(hA, hB, ga, gb);
    STEP(hB, hA, gb, ga);
    STEP(hA, hB, ga, gb);
    STEP(hB, hA, gb, ga);
  }
#undef STEP

  if constexpr (LAYER == 1) {
    dout[XOUT + (size_t)b * 256 + dir * 128 + col] = cs;
  }
}

// ---------------------------------------------------------------------------
extern "C" void kernel_launch(void* const* d_in, const int* in_sizes, int n_in,
                              void* d_out, int out_size, void* d_ws, size_t ws_size,
                              hipStream_t stream) {
  const float* x    = (const float*)d_in[0];
  const float* wxf0 = (const float*)d_in[1];
  const float* whf0 = (const float*)d_in[2];
  const float* wxb0 = (const float*)d_in[3];
  const float* whb0 = (const float*)d_in[4];
  const float* wxf1 = (const float*)d_in[5];
  const float* whf1 = (const float*)d_in[6];
  const float* wxb1 = (const float*)d_in[7];
  const float* whb1 = (const float*)d_in[8];
  const float* bf0  = (const float*)d_in[9];
  const float* bb0  = (const float*)d_in[10];
  const float* bf1  = (const float*)d_in[11];
  const float* bb1  = (const float*)d_in[12];
  float* dout = (float*)d_out;

  // ws: [xp][out0 bf16][sw0][sw1][swh]
  const size_t needF32 = 268435456u + 33554432u + 262144u + 524288u + 524288u;
  bool xpf32 = ws_size >= needF32;
  size_t xpBytes = xpf32 ? 268435456u : 134217728u;
  unsigned char* ws = (unsigned char*)d_ws;
  void* xp = (void*)ws;
  unsigned short* out0 = (unsigned short*)(ws + xpBytes);
  unsigned short* sw0  = (unsigned short*)(ws + xpBytes + 33554432u);
  unsigned short* sw1  = sw0 + 2 * 65536;
  unsigned short* swh  = sw1 + 2 * 131072;

  prep_wx<<<1536, 256, 0, stream>>>(wxf0, wxb0, wxf1, wxb1, sw0, sw1);
  prep_wh<<<1024, 256, 0, stream>>>(whf0, whb0, whf1, whb1, swh);

  if (xpf32) {
    input_proj<0, true><<<dim3(2048, 2), 256, 0, stream>>>(x, nullptr, sw0, bf0, bb0, xp);
    lstm_scan<0, true><<<16, 512, 0, stream>>>(xp, swh, out0, dout);
    input_proj<1, true><<<dim3(2048, 2), 256, 0, stream>>>(nullptr, out0, sw1, bf1, bb1, xp);
    lstm_scan<1, true><<<16, 512, 0, stream>>>(xp, swh, out0, dout);
  } else {
    input_proj<0, false><<<dim3(2048, 2), 256, 0, stream>>>(x, nullptr, sw0, bf0, bb0, xp);
    lstm_scan<0, false><<<16, 512, 0, stream>>>(xp, swh, out0, dout);
    input_proj<1, false><<<dim3(2048, 2), 256, 0, stream>>>(nullptr, out0, sw1, bf1, bb1, xp);
    lstm_scan<1, false><<<16, 512, 0, stream>>>(xp, swh, out0, dout);
  }
}